// Round 14
// baseline (1792.463 us; speedup 1.0000x reference)
//
#include <hip/hip_runtime.h>
#include <hip/hip_bf16.h>
#include <type_traits>

// ---------------- CSR build ----------------
__global__ void hist_kernel(const int* __restrict__ src, const int* __restrict__ dst,
                            int* __restrict__ deg_out, int* __restrict__ deg_in, int E) {
    int e = blockIdx.x * blockDim.x + threadIdx.x;
    if (e < E) {
        atomicAdd(&deg_out[src[e]], 1);
        atomicAdd(&deg_in[dst[e]], 1);
    }
}

__global__ void scan_kernel(const int* __restrict__ deg, int* __restrict__ row_ptr,
                            int* __restrict__ cursor, int n) {
    __shared__ int wsum[16];
    __shared__ int running;
    int tid = threadIdx.x, lane = tid & 63, wid = tid >> 6;
    if (tid == 0) running = 0;
    __syncthreads();
    for (int base = 0; base < n; base += 1024) {
        int i = base + tid;
        int v = (i < n) ? deg[i] : 0;
        int incl = v;
        #pragma unroll
        for (int off = 1; off < 64; off <<= 1) {
            int t = __shfl_up(incl, off);
            if (lane >= off) incl += t;
        }
        if (lane == 63) wsum[wid] = incl;
        __syncthreads();
        if (wid == 0 && lane < 16) {
            int s = wsum[lane], si = s;
            #pragma unroll
            for (int off = 1; off < 16; off <<= 1) {
                int t = __shfl_up(si, off);
                if (lane >= off) si += t;
            }
            wsum[lane] = si - s;  // exclusive
        }
        __syncthreads();
        int excl = running + wsum[wid] + (incl - v);
        if (i < n) { row_ptr[i] = excl; cursor[i] = excl; }
        __syncthreads();
        if (tid == 1023) running = excl + v;
        __syncthreads();
    }
    if (tid == 0) row_ptr[n] = running;
}

// p = cursor[b[e]]++; col[p] = a[e]   (dst-CSR: a=src,b=dst; src-CSR: a=dst,b=src)
__global__ void fill_kernel(const int* __restrict__ a, const int* __restrict__ b,
                            int* __restrict__ cursor, int* __restrict__ col, int E) {
    int e = blockIdx.x * blockDim.x + threadIdx.x;
    if (e < E) {
        int p = atomicAdd(&cursor[b[e]], 1);
        col[p] = a[e];
    }
}

// deterministic neighbor order for the dst-CSR (float gathers depend on order)
__global__ void sort_rows_kernel(const int* __restrict__ row_ptr, int* __restrict__ col, int n) {
    int v = blockIdx.x * blockDim.x + threadIdx.x;
    if (v >= n) return;
    int e0 = row_ptr[v], e1 = row_ptr[v + 1];
    for (int i = e0 + 1; i < e1; ++i) {
        int key = col[i];
        int j = i - 1;
        while (j >= e0 && col[j] > key) { col[j + 1] = col[j]; --j; }
        col[j + 1] = key;
    }
}

// ---------------- masked degrees (fallback path kernels kept) ----------------
__global__ void out_deg_mask_kernel(const int* __restrict__ src, const int* __restrict__ dst,
                                    const float* __restrict__ m, float* __restrict__ so, int E) {
    int e = blockIdx.x * blockDim.x + threadIdx.x;
    if (e < E) {
        float md = m[dst[e]];
        if (md != 0.f) atomicAdd(&so[src[e]], md);
    }
}

__global__ void in_deg_mask_kernel(const int* __restrict__ row_ptr, const int* __restrict__ col,
                                   const float* __restrict__ m, float* __restrict__ si, int n) {
    int v = blockIdx.x * blockDim.x + threadIdx.x;
    if (v < n) {
        float s = 0.f;
        int e1 = row_ptr[v + 1];
        for (int e = row_ptr[v]; e < e1; ++e) s += m[col[e]];
        si[v] = s;
    }
}

__global__ void scale_full_kernel(const int* __restrict__ dout, const int* __restrict__ din,
                                  float* __restrict__ s, float* __restrict__ t, int n) {
    int v = blockIdx.x * blockDim.x + threadIdx.x;
    if (v < n) {
        s[v] = 1.f / sqrtf((float)max(dout[v], 1));
        t[v] = 1.f / sqrtf((float)max(din[v], 1));
    }
}

__global__ void scale_mask_kernel(const float* __restrict__ gate, const float* __restrict__ mask,
                                  const float* __restrict__ so, const float* __restrict__ si,
                                  float* __restrict__ s, float* __restrict__ t, int n) {
    int v = blockIdx.x * blockDim.x + threadIdx.x;
    if (v < n) {
        s[v] = gate[v] * (1.f / sqrtf(fmaxf(so[v], 1.f)));
        t[v] = mask[v] * (1.f / sqrtf(fmaxf(si[v], 1.f)));
    }
}

// R14: fused masked degrees + scales. so/si are sums of 0/1 -> exact in fp32
// in any order -> identical to the atomic version. One dispatch replaces 4.
__global__ void deg_scale_kernel(const int* __restrict__ rp_s, const int* __restrict__ cs,
                                 const int* __restrict__ rp_d, const int* __restrict__ cd,
                                 const float* __restrict__ gate, const float* __restrict__ mask,
                                 float* __restrict__ s, float* __restrict__ t,
                                 float* __restrict__ so_out, float* __restrict__ si_out, int n) {
    int v = blockIdx.x * blockDim.x + threadIdx.x;
    if (v >= n) return;
    float so = 0.f;
    int e1 = rp_s[v + 1];
    for (int e = rp_s[v]; e < e1; ++e) so += mask[cs[e]];
    float si = 0.f;
    e1 = rp_d[v + 1];
    for (int e = rp_d[v]; e < e1; ++e) si += mask[cd[e]];
    s[v] = gate[v] * (1.f / sqrtf(fmaxf(so, 1.f)));
    t[v] = mask[v] * (1.f / sqrtf(fmaxf(si, 1.f)));
    so_out[v] = so;
    si_out[v] = si;
}

// ---------------- aggregation from f32 FEATURES, F=128 (full graph) ----------------
__global__ void agg_feat_128_kernel(const int* __restrict__ row_ptr, const int* __restrict__ col,
                                    const float* __restrict__ X, const float* __restrict__ s,
                                    const float* __restrict__ t, float* __restrict__ out, int n) {
    int tid = threadIdx.x;
    int node = blockIdx.x * 8 + (tid >> 5);
    int f4 = tid & 31;
    if (node >= n) return;
    int e0 = row_ptr[node], e1 = row_ptr[node + 1];
    const float4* X4 = (const float4*)X;
    float ax = 0.f, ay = 0.f, az = 0.f, aw = 0.f;
    int e = e0;
    for (; e + 3 < e1; e += 4) {
        int u0 = col[e], u1 = col[e + 1], u2 = col[e + 2], u3 = col[e + 3];
        float s0 = s[u0], s1 = s[u1], s2 = s[u2], s3 = s[u3];
        float4 x0 = X4[(size_t)u0 * 32 + f4];
        float4 x1 = X4[(size_t)u1 * 32 + f4];
        float4 x2 = X4[(size_t)u2 * 32 + f4];
        float4 x3 = X4[(size_t)u3 * 32 + f4];
        ax += s0 * x0.x; ay += s0 * x0.y; az += s0 * x0.z; aw += s0 * x0.w;
        ax += s1 * x1.x; ay += s1 * x1.y; az += s1 * x1.z; aw += s1 * x1.w;
        ax += s2 * x2.x; ay += s2 * x2.y; az += s2 * x2.z; aw += s2 * x2.w;
        ax += s3 * x3.x; ay += s3 * x3.y; az += s3 * x3.z; aw += s3 * x3.w;
    }
    for (; e < e1; ++e) {
        int u = col[e];
        float sc = s[u];
        float4 q = X4[(size_t)u * 32 + f4];
        ax += sc * q.x; ay += sc * q.y; az += sc * q.z; aw += sc * q.w;
    }
    float tv = t[node];
    float4 r; r.x = ax * tv; r.y = ay * tv; r.z = az * tv; r.w = aw * tv;
    ((float4*)out)[(size_t)node * 32 + f4] = r;
}

// ---------------- aggregation over f32 workspace, F=256 ----------------
template <bool MASKED>
__global__ void agg_f32_256_kernel(const int* __restrict__ row_ptr, const int* __restrict__ col,
                                   const float* __restrict__ X, const float* __restrict__ s,
                                   const float* __restrict__ t, float* __restrict__ out, int n) {
    int tid = threadIdx.x;
    int node = blockIdx.x * 4 + (tid >> 6);
    int f4 = tid & 63;
    if (node >= n) return;
    float tv = t[node];
    if (MASKED && tv == 0.f) return;
    int e0 = row_ptr[node], e1 = row_ptr[node + 1];
    const float4* X4 = (const float4*)X;
    float ax = 0.f, ay = 0.f, az = 0.f, aw = 0.f;
    int e = e0;
    for (; e + 3 < e1; e += 4) {
        int u0 = col[e], u1 = col[e + 1], u2 = col[e + 2], u3 = col[e + 3];
        float s0 = s[u0], s1 = s[u1], s2 = s[u2], s3 = s[u3];
        if (!MASKED) {
            float4 x0 = X4[(size_t)u0 * 64 + f4];
            float4 x1 = X4[(size_t)u1 * 64 + f4];
            float4 x2 = X4[(size_t)u2 * 64 + f4];
            float4 x3 = X4[(size_t)u3 * 64 + f4];
            ax += s0 * x0.x; ay += s0 * x0.y; az += s0 * x0.z; aw += s0 * x0.w;
            ax += s1 * x1.x; ay += s1 * x1.y; az += s1 * x1.z; aw += s1 * x1.w;
            ax += s2 * x2.x; ay += s2 * x2.y; az += s2 * x2.z; aw += s2 * x2.w;
            ax += s3 * x3.x; ay += s3 * x3.y; az += s3 * x3.z; aw += s3 * x3.w;
        } else {
            if (s0 != 0.f) { float4 x = X4[(size_t)u0 * 64 + f4];
                ax += s0 * x.x; ay += s0 * x.y; az += s0 * x.z; aw += s0 * x.w; }
            if (s1 != 0.f) { float4 x = X4[(size_t)u1 * 64 + f4];
                ax += s1 * x.x; ay += s1 * x.y; az += s1 * x.z; aw += s1 * x.w; }
            if (s2 != 0.f) { float4 x = X4[(size_t)u2 * 64 + f4];
                ax += s2 * x.x; ay += s2 * x.y; az += s2 * x.z; aw += s2 * x.w; }
            if (s3 != 0.f) { float4 x = X4[(size_t)u3 * 64 + f4];
                ax += s3 * x.x; ay += s3 * x.y; az += s3 * x.z; aw += s3 * x.w; }
        }
    }
    for (; e < e1; ++e) {
        int u = col[e];
        float sc = s[u];
        if (!MASKED || sc != 0.f) {
            float4 xv = X4[(size_t)u * 64 + f4];
            ax += sc * xv.x; ay += sc * xv.y; az += sc * xv.z; aw += sc * xv.w;
        }
    }
    float4 r; r.x = ax * tv; r.y = ay * tv; r.z = az * tv; r.w = aw * tv;
    ((float4*)out)[(size_t)node * 64 + f4] = r;
}

// R14: masked agg over compacted node list (bit-identical per node; only
// selected rows written -> downstream consumers read only those / use masks).
__global__ void agg_rows_256_kernel(const int* __restrict__ row_ptr, const int* __restrict__ col,
                                    const float* __restrict__ X, const float* __restrict__ s,
                                    const float* __restrict__ t, const int* __restrict__ idx,
                                    int Mc, float* __restrict__ out) {
    int tid = threadIdx.x;
    int li = blockIdx.x * 4 + (tid >> 6);
    int f4 = tid & 63;
    if (li >= Mc) return;
    int node = idx[li];
    float tv = t[node];
    int e0 = row_ptr[node], e1 = row_ptr[node + 1];
    const float4* X4 = (const float4*)X;
    float ax = 0.f, ay = 0.f, az = 0.f, aw = 0.f;
    int e = e0;
    for (; e + 3 < e1; e += 4) {
        int u0 = col[e], u1 = col[e + 1], u2 = col[e + 2], u3 = col[e + 3];
        float s0 = s[u0], s1 = s[u1], s2 = s[u2], s3 = s[u3];
        if (s0 != 0.f) { float4 x = X4[(size_t)u0 * 64 + f4];
            ax += s0 * x.x; ay += s0 * x.y; az += s0 * x.z; aw += s0 * x.w; }
        if (s1 != 0.f) { float4 x = X4[(size_t)u1 * 64 + f4];
            ax += s1 * x.x; ay += s1 * x.y; az += s1 * x.z; aw += s1 * x.w; }
        if (s2 != 0.f) { float4 x = X4[(size_t)u2 * 64 + f4];
            ax += s2 * x.x; ay += s2 * x.y; az += s2 * x.z; aw += s2 * x.w; }
        if (s3 != 0.f) { float4 x = X4[(size_t)u3 * 64 + f4];
            ax += s3 * x.x; ay += s3 * x.y; az += s3 * x.z; aw += s3 * x.w; }
    }
    for (; e < e1; ++e) {
        int u = col[e];
        float sc = s[u];
        if (sc != 0.f) {
            float4 xv = X4[(size_t)u * 64 + f4];
            ax += sc * xv.x; ay += sc * xv.y; az += sc * xv.z; aw += sc * xv.w;
        }
    }
    float4 r; r.x = ax * tv; r.y = ay * tv; r.z = az * tv; r.w = aw * tv;
    ((float4*)out)[(size_t)node * 64 + f4] = r;
}

// ---------------- post-GEMM 128-dim gather for dec1 ----------------
__global__ void agg_bias_128_kernel(const int* __restrict__ row_ptr, const int* __restrict__ col,
                                    const float* __restrict__ P, const float* __restrict__ t,
                                    const float* __restrict__ bias, float* __restrict__ out, int n) {
    int tid = threadIdx.x;
    int node = blockIdx.x * 8 + (tid >> 5);
    int f4 = tid & 31;
    if (node >= n) return;
    int e0 = row_ptr[node], e1 = row_ptr[node + 1];
    const float4* P4 = (const float4*)P;
    float ax = 0.f, ay = 0.f, az = 0.f, aw = 0.f;
    int e = e0;
    for (; e + 3 < e1; e += 4) {
        int u0 = col[e], u1 = col[e + 1], u2 = col[e + 2], u3 = col[e + 3];
        float4 x0 = P4[(size_t)u0 * 32 + f4];
        float4 x1 = P4[(size_t)u1 * 32 + f4];
        float4 x2 = P4[(size_t)u2 * 32 + f4];
        float4 x3 = P4[(size_t)u3 * 32 + f4];
        ax += x0.x; ay += x0.y; az += x0.z; aw += x0.w;
        ax += x1.x; ay += x1.y; az += x1.z; aw += x1.w;
        ax += x2.x; ay += x2.y; az += x2.z; aw += x2.w;
        ax += x3.x; ay += x3.y; az += x3.z; aw += x3.w;
    }
    for (; e < e1; ++e) {
        int u = col[e];
        float4 q = P4[(size_t)u * 32 + f4];
        ax += q.x; ay += q.y; az += q.z; aw += q.w;
    }
    float tv = t[node];
    float4 bv = ((const float4*)bias)[f4];
    float4 r;
    r.x = ax * tv + bv.x; r.y = ay * tv + bv.y;
    r.z = az * tv + bv.z; r.w = aw * tv + bv.w;
    ((float4*)out)[(size_t)node * 32 + f4] = r;
}

// ---------------- GEMM (full rows): 64x128 tile, 4x(4+4) micro-tile ----------------
template <bool RELU>
__global__ __launch_bounds__(256) void gemm_kernel(const float* __restrict__ A,
                                                   const float* __restrict__ W,
                                                   const float* __restrict__ bias,
                                                   const float* __restrict__ mask,
                                                   const float* __restrict__ rowscale,
                                                   float* __restrict__ C, int M, int K, int Nn) {
    __shared__ float As[16][68];
    __shared__ float Bs[16][132];
    int tid = threadIdx.x;
    int bm = blockIdx.x * 64, bn = blockIdx.y * 128;
    int mA = tid >> 2, kqA = (tid & 3) * 4;
    int kB = tid >> 4, nqB = (tid & 15) * 8;
    int tm = (tid >> 4) * 4, tn = (tid & 15) * 4;
    float acc[4][8] = {};
    float rs = rowscale ? rowscale[bm + mA] : 1.f;
    for (int k0 = 0; k0 < K; k0 += 16) {
        float4 av = *(const float4*)(A + (size_t)(bm + mA) * K + k0 + kqA);
        As[kqA + 0][mA] = av.x * rs; As[kqA + 1][mA] = av.y * rs;
        As[kqA + 2][mA] = av.z * rs; As[kqA + 3][mA] = av.w * rs;
        const float* wp = W + (size_t)(k0 + kB) * Nn + bn + nqB;
        *(float4*)&Bs[kB][nqB]     = *(const float4*)wp;
        *(float4*)&Bs[kB][nqB + 4] = *(const float4*)(wp + 4);
        __syncthreads();
        #pragma unroll
        for (int kk = 0; kk < 16; ++kk) {
            float4 a  = *(const float4*)&As[kk][tm];
            float4 b0 = *(const float4*)&Bs[kk][tn];
            float4 b1 = *(const float4*)&Bs[kk][tn + 64];
            float ar[4] = {a.x, a.y, a.z, a.w};
            float br[8] = {b0.x, b0.y, b0.z, b0.w, b1.x, b1.y, b1.z, b1.w};
            #pragma unroll
            for (int i2 = 0; i2 < 4; i2++)
                #pragma unroll
                for (int j = 0; j < 8; j++) acc[i2][j] += ar[i2] * br[j];
        }
        __syncthreads();
    }
    #pragma unroll
    for (int i2 = 0; i2 < 4; i2++) {
        int row = bm + tm + i2;
        if (row < M) {
            float mv = mask ? mask[row] : 1.f;
            float o[8];
            #pragma unroll
            for (int j = 0; j < 8; j++) {
                int cj = (j < 4) ? (tn + j) : (64 + tn + j - 4);
                float x = acc[i2][j] + (bias ? bias[bn + cj] : 0.f);
                if (RELU) x = fmaxf(x, 0.f);
                o[j] = x * mv;
            }
            float* cp = C + (size_t)row * Nn + bn;
            *(float4*)(cp + tn)      = make_float4(o[0], o[1], o[2], o[3]);
            *(float4*)(cp + 64 + tn) = make_float4(o[4], o[5], o[6], o[7]);
        }
    }
}

// ---------------- GEMM over compacted row list ----------------
template <bool RELU>
__global__ __launch_bounds__(256) void gemm_rows_kernel(const float* __restrict__ A,
                                                        const float* __restrict__ W,
                                                        const float* __restrict__ bias,
                                                        const int* __restrict__ idx, int Mc,
                                                        float* __restrict__ C, int K, int Nn) {
    __shared__ float As[16][68];
    __shared__ float Bs[16][132];
    __shared__ int ridx[64];
    int tid = threadIdx.x;
    int bm = blockIdx.x * 64, bn = blockIdx.y * 128;
    if (tid < 64) {
        int r = bm + tid;
        ridx[tid] = (r < Mc) ? idx[r] : idx[0];
    }
    __syncthreads();
    int mA = tid >> 2, kqA = (tid & 3) * 4;
    int kB = tid >> 4, nqB = (tid & 15) * 8;
    int tm = (tid >> 4) * 4, tn = (tid & 15) * 4;
    int rA = ridx[mA];
    float acc[4][8] = {};
    for (int k0 = 0; k0 < K; k0 += 16) {
        float4 av = *(const float4*)(A + (size_t)rA * K + k0 + kqA);
        As[kqA + 0][mA] = av.x; As[kqA + 1][mA] = av.y;
        As[kqA + 2][mA] = av.z; As[kqA + 3][mA] = av.w;
        const float* wp = W + (size_t)(k0 + kB) * Nn + bn + nqB;
        *(float4*)&Bs[kB][nqB]     = *(const float4*)wp;
        *(float4*)&Bs[kB][nqB + 4] = *(const float4*)(wp + 4);
        __syncthreads();
        #pragma unroll
        for (int kk = 0; kk < 16; ++kk) {
            float4 a  = *(const float4*)&As[kk][tm];
            float4 b0 = *(const float4*)&Bs[kk][tn];
            float4 b1 = *(const float4*)&Bs[kk][tn + 64];
            float ar[4] = {a.x, a.y, a.z, a.w};
            float br[8] = {b0.x, b0.y, b0.z, b0.w, b1.x, b1.y, b1.z, b1.w};
            #pragma unroll
            for (int i2 = 0; i2 < 4; i2++)
                #pragma unroll
                for (int j = 0; j < 8; j++) acc[i2][j] += ar[i2] * br[j];
        }
        __syncthreads();
    }
    #pragma unroll
    for (int i2 = 0; i2 < 4; i2++) {
        int r = bm + tm + i2;
        if (r < Mc) {
            int row = ridx[tm + i2];
            float o[8];
            #pragma unroll
            for (int j = 0; j < 8; j++) {
                int cj = (j < 4) ? (tn + j) : (64 + tn + j - 4);
                float x = acc[i2][j] + bias[bn + cj];
                if (RELU) x = fmaxf(x, 0.f);
                o[j] = x;
            }
            float* cp = C + (size_t)row * Nn + bn;
            *(float4*)(cp + tn)      = make_float4(o[0], o[1], o[2], o[3]);
            *(float4*)(cp + 64 + tn) = make_float4(o[4], o[5], o[6], o[7]);
        }
    }
}

// ---------------- pooling score ----------------
__global__ void score_kernel(const float* __restrict__ H, const float* __restrict__ Wp,
                             const float* __restrict__ bp, const float* __restrict__ mask,
                             float* __restrict__ scores, float* __restrict__ keys, int n) {
    int lane = threadIdx.x & 63;
    int node = blockIdx.x * 4 + (threadIdx.x >> 6);
    if (node >= n) return;
    float4 hv = ((const float4*)(H + (size_t)node * 256))[lane];
    float4 wq = ((const float4*)Wp)[lane];
    float d = hv.x * wq.x + hv.y * wq.y + hv.z * wq.z + hv.w * wq.w;
    #pragma unroll
    for (int off = 32; off > 0; off >>= 1) d += __shfl_down(d, off);
    if (lane == 0) {
        float sc = 1.f / (1.f + expf(-(d + bp[0])));
        scores[node] = sc;
        keys[node] = (mask && mask[node] == 0.f) ? -1e9f : sc;
    }
}

// ---------------- top-K selection ----------------
__device__ __forceinline__ unsigned key_u(float f) {
    unsigned u = __float_as_uint(f);
    return (u & 0x80000000u) ? ~u : (u | 0x80000000u);
}

__device__ __forceinline__ void wave_hist_add(int* __restrict__ hist, unsigned bin, bool valid) {
    int lane = threadIdx.x & 63;
    while (true) {
        unsigned long long vmask = __ballot(valid);
        if (vmask == 0ull) break;
        int leader = __ffsll((long long)vmask) - 1;
        unsigned lbin = (unsigned)__shfl((int)bin, leader);
        bool match = valid && (bin == lbin);
        unsigned long long mmask = __ballot(match);
        if (lane == leader) atomicAdd(&hist[lbin], __popcll(mmask));
        if (match) valid = false;
    }
}

// -------- fallback: single block radix select --------
__global__ void topk_kernel(const float* __restrict__ keys, const float* __restrict__ scores,
                            float* __restrict__ nm, float* __restrict__ gate, int n, int K) {
    __shared__ int hist[256];
    __shared__ unsigned sh_prefix;
    __shared__ int sh_krem;
    __shared__ int sh_running;
    __shared__ int wsum[16];
    int tid = threadIdx.x, lane = tid & 63, wid = tid >> 6;
    if (tid == 0) { sh_prefix = 0u; sh_krem = K; sh_running = 0; }
    __syncthreads();
    for (int pass = 0; pass < 4; ++pass) {
        int shift = 24 - pass * 8;
        if (tid < 256) hist[tid] = 0;
        __syncthreads();
        unsigned pmask = (pass == 0) ? 0u : (0xFFFFFFFFu << (shift + 8));
        unsigned prefix = sh_prefix;
        for (int i = tid; i < n; i += 1024) {
            unsigned u = key_u(keys[i]);
            if ((u & pmask) == prefix) atomicAdd(&hist[(u >> shift) & 0xFF], 1);
        }
        __syncthreads();
        if (tid == 0) {
            int krem = sh_krem;
            int b;
            for (b = 255; b > 0; --b) {
                int c = hist[b];
                if (c >= krem) break;
                krem -= c;
            }
            sh_prefix = prefix | ((unsigned)b << shift);
            sh_krem = krem;
        }
        __syncthreads();
    }
    unsigned Tkey = sh_prefix;
    int need_eq = sh_krem;
    for (int base = 0; base < n; base += 1024) {
        int i = base + tid;
        unsigned u = 0; int flagv = 0;
        if (i < n) { u = key_u(keys[i]); flagv = (u == Tkey) ? 1 : 0; }
        unsigned long long bal = __ballot(flagv);
        int rank_w = __popcll(bal & ((1ull << lane) - 1ull));
        if (lane == 63) wsum[wid] = __popcll(bal);
        __syncthreads();
        int woff = 0;
        for (int w = 0; w < wid; ++w) woff += wsum[w];
        int grank = sh_running + woff + rank_w;
        if (i < n) {
            float v = (u > Tkey) ? 1.f : ((flagv && grank < need_eq) ? 1.f : 0.f);
            nm[i] = v;
            gate[i] = v * scores[i];
        }
        __syncthreads();
        if (tid == 0) {
            int tot = 0;
            for (int w = 0; w < 16; ++w) tot += wsum[w];
            sh_running += tot;
        }
        __syncthreads();
    }
}

// -------- fast path: grid-wide radix select, 2 passes of 16 bits --------
__global__ void topk_hist1(const float* __restrict__ keys, int n, int* __restrict__ hist) {
    int i = blockIdx.x * blockDim.x + threadIdx.x;
    unsigned bin = 0; bool valid = (i < n);
    if (valid) bin = key_u(keys[i]) >> 16;
    wave_hist_add(hist, bin, valid);
}

// scan1: finds threshold bucket; ALSO zeroes its bins afterward (own-bins
// only -> race-free) so hist2 sees a clean histogram without a memset.
__global__ void topk_scan1(int* __restrict__ hist, int K, int* __restrict__ sel) {
    __shared__ int arr[1024];
    int tid = threadIdx.x;
    int base = tid * 64;
    int local = 0;
    #pragma unroll 8
    for (int b = 0; b < 64; ++b) local += hist[base + b];
    arr[tid] = local;
    __syncthreads();
    for (int off = 1; off < 1024; off <<= 1) {
        int v = (tid + off < 1024) ? arr[tid + off] : 0;
        __syncthreads();
        arr[tid] += v;
        __syncthreads();
    }
    int above = arr[tid] - local;
    if (above < K && arr[tid] >= K) {
        int run = above;
        for (int b = base + 63; b >= base; --b) {
            int c = hist[b];
            if (run + c >= K) { sel[0] = b; sel[1] = K - run; break; }
            run += c;
        }
    }
    #pragma unroll 8
    for (int b = 0; b < 64; ++b) hist[base + b] = 0;
}

__global__ void topk_hist2(const float* __restrict__ keys, int n, const int* __restrict__ sel,
                           int* __restrict__ hist) {
    int i = blockIdx.x * blockDim.x + threadIdx.x;
    unsigned bin = 0; bool valid = false;
    if (i < n) {
        unsigned u = key_u(keys[i]);
        if ((int)(u >> 16) == sel[0]) { bin = u & 0xFFFF; valid = true; }
    }
    wave_hist_add(hist, bin, valid);
}

// scan2: finds Tkey/need_eq, zeroes bins (for the next pool's hist1), and
// resets tie + compaction counters.
__global__ void topk_scan2(int* __restrict__ hist, int* __restrict__ sel,
                           int* __restrict__ tie_cnt, int* __restrict__ ccnt) {
    __shared__ int arr[1024];
    int tid = threadIdx.x;
    if (tid == 0) { *tie_cnt = 0; *ccnt = 0; }
    int K = sel[1];
    int base = tid * 64;
    int local = 0;
    #pragma unroll 8
    for (int b = 0; b < 64; ++b) local += hist[base + b];
    arr[tid] = local;
    __syncthreads();
    for (int off = 1; off < 1024; off <<= 1) {
        int v = (tid + off < 1024) ? arr[tid + off] : 0;
        __syncthreads();
        arr[tid] += v;
        __syncthreads();
    }
    int above = arr[tid] - local;
    if (above < K && arr[tid] >= K) {
        int run = above;
        for (int b = base + 63; b >= base; --b) {
            int c = hist[b];
            if (run + c >= K) {
                sel[2] = (int)((((unsigned)sel[0]) << 16) | (unsigned)b);
                sel[3] = K - run;
                break;
            }
            run += c;
        }
    }
    #pragma unroll 8
    for (int b = 0; b < 64; ++b) hist[base + b] = 0;
}

// mark: writes nm/gate AND appends selected rows to idx (R14 fused compact).
__global__ void topk_mark(const float* __restrict__ keys, const float* __restrict__ scores,
                          const int* __restrict__ sel, float* __restrict__ nm,
                          float* __restrict__ gate, int* __restrict__ tie_list,
                          int* __restrict__ tie_cnt, int* __restrict__ sidx,
                          int* __restrict__ ccnt, int n) {
    int i = blockIdx.x * blockDim.x + threadIdx.x;
    if (i >= n) return;
    unsigned Tkey = (unsigned)sel[2];
    unsigned u = key_u(keys[i]);
    float v = 0.f;
    if (u > Tkey) { v = 1.f; int p = atomicAdd(ccnt, 1); sidx[p] = i; }
    else if (u == Tkey) { int p = atomicAdd(tie_cnt, 1); tie_list[p] = i; }
    nm[i] = v;
    gate[i] = v * scores[i];
}

__global__ void topk_ties(const float* __restrict__ scores, const int* __restrict__ sel,
                          const int* __restrict__ tie_list, const int* __restrict__ tie_cnt,
                          float* __restrict__ nm, float* __restrict__ gate,
                          int* __restrict__ sidx, int* __restrict__ ccnt) {
    int cnt = *tie_cnt;
    int need = sel[3];
    for (int j = threadIdx.x; j < cnt; j += blockDim.x) {
        int idx = tie_list[j];
        int rank = 0;
        for (int k2 = 0; k2 < cnt; ++k2) rank += (tie_list[k2] < idx) ? 1 : 0;
        if (rank < need) {
            nm[idx] = 1.f; gate[idx] = scores[idx];
            int p = atomicAdd(ccnt, 1); sidx[p] = idx;
        }
    }
}

// ---------------- adds ----------------
__global__ void add_mask_kernel(float* __restrict__ A, const float* __restrict__ B,
                                const float* __restrict__ mask, int n4) {
    int i = blockIdx.x * blockDim.x + threadIdx.x;
    if (i < n4) {
        float4 a = ((float4*)A)[i];
        float4 b = ((const float4*)B)[i];
        if (mask && mask[i >> 6] == 0.f) { a.x = 0.f; a.y = 0.f; a.z = 0.f; a.w = 0.f; }
        a.x += b.x; a.y += b.y; a.z += b.z; a.w += b.w;
        ((float4*)A)[i] = a;
    }
}

extern "C" void kernel_launch(void* const* d_in, const int* in_sizes, int n_in,
                              void* d_out, int out_size, void* d_ws, size_t ws_size,
                              hipStream_t stream) {
    const int n = in_sizes[0] / 128;   // 50000
    const int E = in_sizes[1];         // 800000
    const int NPAD = ((n + 63) / 64) * 64;
    const int K1 = 25000, K2 = 12500;

    const float* features = (const float*)d_in[0];
    const int* src = (const int*)d_in[1];
    const int* dst = (const int*)d_in[2];
    const float* W_embed = (const float*)d_in[3];
    const float* b_embed = (const float*)d_in[4];
    const float* W_enc0  = (const float*)d_in[5];
    const float* b_enc0  = (const float*)d_in[6];
    const float* W_enc1  = (const float*)d_in[7];
    const float* b_enc1  = (const float*)d_in[8];
    const float* W_p0    = (const float*)d_in[9];
    const float* b_p0    = (const float*)d_in[10];
    const float* W_p1    = (const float*)d_in[11];
    const float* b_p1    = (const float*)d_in[12];
    const float* W_bot   = (const float*)d_in[13];
    const float* b_bot   = (const float*)d_in[14];
    const float* W_dec0  = (const float*)d_in[15];
    const float* b_dec0  = (const float*)d_in[16];
    const float* W_dec1  = (const float*)d_in[17];
    const float* b_dec1  = (const float*)d_in[18];
    float* out_f = (float*)d_out;

    char* ws = (char*)d_ws;
    size_t off = 0;
    auto alloc = [&](size_t bytes) -> void* {
        void* p = ws + off;
        off += (bytes + 255) & ~(size_t)255;
        return p;
    };
    (void)alloc(256);  // pad
    int* row_ptr  = (int*)alloc((size_t)(n + 1) * 4);
    int* cursor   = (int*)alloc((size_t)n * 4);
    int* col      = (int*)alloc((size_t)E * 4);
    int* deg_out_i= (int*)alloc((size_t)n * 4);
    int* deg_in_i = (int*)alloc((size_t)n * 4);
    float* so_m1  = (float*)alloc((size_t)n * 4);
    float* si_m1  = (float*)alloc((size_t)n * 4);
    float* so_m2  = (float*)alloc((size_t)n * 4);
    float* si_m2  = (float*)alloc((size_t)n * 4);
    float* sarr   = (float*)alloc((size_t)n * 4);
    float* tarr   = (float*)alloc((size_t)n * 4);
    float* scores1= (float*)alloc((size_t)n * 4);
    float* keys1  = (float*)alloc((size_t)n * 4);
    float* scores2= (float*)alloc((size_t)n * 4);
    float* keys2  = (float*)alloc((size_t)n * 4);
    float* nm1    = (float*)alloc((size_t)n * 4);
    float* gate1  = (float*)alloc((size_t)n * 4);
    float* nm2    = (float*)alloc((size_t)n * 4);
    float* gate2  = (float*)alloc((size_t)n * 4);
    size_t big = (size_t)NPAD * 256 * 4;
    float* A = (float*)alloc(big);
    float* B = (float*)alloc(big);
    float* C = (float*)alloc(big);
    float* D = (float*)alloc(big);
    // ---- tail ----
    int* rhist    = (int*)alloc(65536 * 4);
    int* sel      = (int*)alloc(256);
    int* tie_cnt  = (int*)alloc(256);
    int* tie_list = (int*)alloc((size_t)n * 4);
    float* s0     = (float*)alloc((size_t)n * 4);
    float* t0     = (float*)alloc((size_t)n * 4);
    int* idx1     = (int*)alloc((size_t)n * 4);
    int* idx2     = (int*)alloc((size_t)n * 4);
    int* ccnt     = (int*)alloc(256);
    int* row_ptr_s= (int*)alloc((size_t)(n + 1) * 4);   // R14: CSR by src
    int* cursor_s = (int*)alloc((size_t)n * 4);
    int* col_s    = (int*)alloc((size_t)E * 4);
    bool fast = (off <= ws_size);

    dim3 blk(256);
    int gE = (E + 255) / 256;
    int gN = (n + 255) / 256;
    int gAgg256 = (n + 3) / 4;
    int gAgg128 = (n + 7) / 8;
    int gAggK1 = (K1 + 3) / 4;
    int gAggK2 = (K2 + 3) / 4;
    int gScore = (n + 3) / 4;
    dim3 gemm_g(NPAD / 64, 2);
    dim3 gemm_g128(NPAD / 64, 1);
    dim3 gemm_gK1((K1 + 63) / 64, 2);
    dim3 gemm_gK2((K2 + 63) / 64, 2);
    int gAdd = (n * 64 + 255) / 256;

    auto run_topk = [&](const float* keys, const float* scores, float* nm, float* gate,
                        int K, int* sidx, int* cc) {
        if (fast) {
            topk_hist1<<<gN, blk, 0, stream>>>(keys, n, rhist);
            topk_scan1<<<1, 1024, 0, stream>>>(rhist, K, sel);
            topk_hist2<<<gN, blk, 0, stream>>>(keys, n, sel, rhist);
            topk_scan2<<<1, 1024, 0, stream>>>(rhist, sel, tie_cnt, cc);
            topk_mark<<<gN, blk, 0, stream>>>(keys, scores, sel, nm, gate, tie_list, tie_cnt,
                                              sidx, cc, n);
            topk_ties<<<1, 256, 0, stream>>>(scores, sel, tie_list, tie_cnt, nm, gate, sidx, cc);
        } else {
            topk_kernel<<<1, 1024, 0, stream>>>(keys, scores, nm, gate, n, K);
        }
    };
    float* sF = fast ? s0 : sarr;
    float* tF = fast ? t0 : tarr;

    // ---- CSR build (dst-CSR sorted; src-CSR unsorted: only used for exact 0/1 sums) ----
    hipMemsetAsync(deg_out_i, 0, (size_t)n * 4, stream);
    hipMemsetAsync(deg_in_i, 0, (size_t)n * 4, stream);
    if (fast) hipMemsetAsync(rhist, 0, 65536 * 4, stream);   // scans re-zero afterward
    hist_kernel<<<gE, blk, 0, stream>>>(src, dst, deg_out_i, deg_in_i, E);
    scan_kernel<<<1, 1024, 0, stream>>>(deg_in_i, row_ptr, cursor, n);
    fill_kernel<<<gE, blk, 0, stream>>>(src, dst, cursor, col, E);
    sort_rows_kernel<<<gN, blk, 0, stream>>>(row_ptr, col, n);
    if (fast) {
        scan_kernel<<<1, 1024, 0, stream>>>(deg_out_i, row_ptr_s, cursor_s, n);
        fill_kernel<<<gE, blk, 0, stream>>>(dst, src, cursor_s, col_s, E);
    }

    // ---- full-graph degree scales ----
    scale_full_kernel<<<gN, blk, 0, stream>>>(deg_out_i, deg_in_i, sF, tF, n);

    // ---- embed GCN (full graph) -> A ----
    agg_feat_128_kernel<<<gAgg128, blk, 0, stream>>>(row_ptr, col, features, sF, tF, D, n);
    gemm_kernel<true><<<gemm_g, blk, 0, stream>>>(D, W_embed, b_embed, nullptr, nullptr, A, n, 128, 256);

    // ---- enc0 (full graph); hidden0 = B ----
    agg_f32_256_kernel<false><<<gAgg256, blk, 0, stream>>>(row_ptr, col, A, sF, tF, D, n);
    gemm_kernel<true><<<gemm_g, blk, 0, stream>>>(D, W_enc0, b_enc0, nullptr, nullptr, B, n, 256, 256);

    // ---- pool0 ----
    score_kernel<<<gScore, blk, 0, stream>>>(B, W_p0, b_p0, nullptr, scores1, keys1, n);
    run_topk(keys1, scores1, nm1, gate1, K1, idx1, ccnt);

    // ---- enc1 (mask m1, gated input); hidden1 = C ----
    if (fast) {
        deg_scale_kernel<<<gN, blk, 0, stream>>>(row_ptr_s, col_s, row_ptr, col, gate1, nm1,
                                                 sarr, tarr, so_m1, si_m1, n);
        agg_rows_256_kernel<<<gAggK1, blk, 0, stream>>>(row_ptr, col, B, sarr, tarr, idx1, K1, D);
        gemm_rows_kernel<true><<<gemm_gK1, blk, 0, stream>>>(D, W_enc1, b_enc1, idx1, K1, C, 256, 256);
    } else {
        hipMemsetAsync(so_m1, 0, (size_t)n * 4, stream);
        out_deg_mask_kernel<<<gE, blk, 0, stream>>>(src, dst, nm1, so_m1, E);
        in_deg_mask_kernel<<<gN, blk, 0, stream>>>(row_ptr, col, nm1, si_m1, n);
        scale_mask_kernel<<<gN, blk, 0, stream>>>(gate1, nm1, so_m1, si_m1, sarr, tarr, n);
        agg_f32_256_kernel<true><<<gAgg256, blk, 0, stream>>>(row_ptr, col, B, sarr, tarr, D, n);
        gemm_kernel<true><<<gemm_g, blk, 0, stream>>>(D, W_enc1, b_enc1, nm1, nullptr, C, n, 256, 256);
    }

    // ---- pool1 ----
    score_kernel<<<gScore, blk, 0, stream>>>(C, W_p1, b_p1, nm1, scores2, keys2, n);
    run_topk(keys2, scores2, nm2, gate2, K2, idx2, ccnt + 1);

    // ---- bottleneck (mask m2, gated input) -> A ----
    if (fast) {
        deg_scale_kernel<<<gN, blk, 0, stream>>>(row_ptr_s, col_s, row_ptr, col, gate2, nm2,
                                                 sarr, tarr, so_m2, si_m2, n);
        agg_rows_256_kernel<<<gAggK2, blk, 0, stream>>>(row_ptr, col, C, sarr, tarr, idx2, K2, D);
        gemm_rows_kernel<true><<<gemm_gK2, blk, 0, stream>>>(D, W_bot, b_bot, idx2, K2, A, 256, 256);
    } else {
        hipMemsetAsync(so_m2, 0, (size_t)n * 4, stream);
        out_deg_mask_kernel<<<gE, blk, 0, stream>>>(src, dst, nm2, so_m2, E);
        in_deg_mask_kernel<<<gN, blk, 0, stream>>>(row_ptr, col, nm2, si_m2, n);
        scale_mask_kernel<<<gN, blk, 0, stream>>>(gate2, nm2, so_m2, si_m2, sarr, tarr, n);
        agg_f32_256_kernel<true><<<gAgg256, blk, 0, stream>>>(row_ptr, col, C, sarr, tarr, D, n);
        gemm_kernel<true><<<gemm_g, blk, 0, stream>>>(D, W_bot, b_bot, nm2, nullptr, A, n, 256, 256);
    }

    // ---- dec0: h = (m2? bot : 0) + hidden1, GCN mask m1 -> A ----
    add_mask_kernel<<<gAdd, blk, 0, stream>>>(A, C, fast ? nm2 : nullptr, n * 64);
    scale_mask_kernel<<<gN, blk, 0, stream>>>(nm1, nm1, so_m1, si_m1, sarr, tarr, n);
    if (fast) {
        agg_rows_256_kernel<<<gAggK1, blk, 0, stream>>>(row_ptr, col, A, sarr, tarr, idx1, K1, D);
        gemm_rows_kernel<true><<<gemm_gK1, blk, 0, stream>>>(D, W_dec0, b_dec0, idx1, K1, A, 256, 256);
    } else {
        agg_f32_256_kernel<true><<<gAgg256, blk, 0, stream>>>(row_ptr, col, A, sarr, tarr, D, n);
        gemm_kernel<true><<<gemm_g, blk, 0, stream>>>(D, W_dec0, b_dec0, nm1, nullptr, A, n, 256, 256);
    }

    // ---- dec1 (reordered, final layer) ----
    add_mask_kernel<<<gAdd, blk, 0, stream>>>(A, B, fast ? nm1 : nullptr, n * 64);
    if (!fast)
        scale_full_kernel<<<gN, blk, 0, stream>>>(deg_out_i, deg_in_i, sarr, tarr, n);
    gemm_kernel<false><<<gemm_g128, blk, 0, stream>>>(A, W_dec1, nullptr, nullptr, sF, C, n, 256, 128);
    agg_bias_128_kernel<<<gAgg128, blk, 0, stream>>>(row_ptr, col, C, tF, b_dec1, out_f, n);

    (void)n_in; (void)out_size;
}

// Round 15
// 1393.880 us; speedup vs baseline: 1.2860x; 1.2860x over previous
//
#include <hip/hip_runtime.h>
#include <hip/hip_bf16.h>
#include <type_traits>

// ---------------- CSR build ----------------
__global__ void hist_kernel(const int* __restrict__ src, const int* __restrict__ dst,
                            int* __restrict__ deg_out, int* __restrict__ deg_in, int E) {
    int e = blockIdx.x * blockDim.x + threadIdx.x;
    if (e < E) {
        atomicAdd(&deg_out[src[e]], 1);
        atomicAdd(&deg_in[dst[e]], 1);
    }
}

__global__ void scan_kernel(const int* __restrict__ deg, int* __restrict__ row_ptr,
                            int* __restrict__ cursor, int n) {
    __shared__ int wsum[16];
    __shared__ int running;
    int tid = threadIdx.x, lane = tid & 63, wid = tid >> 6;
    if (tid == 0) running = 0;
    __syncthreads();
    for (int base = 0; base < n; base += 1024) {
        int i = base + tid;
        int v = (i < n) ? deg[i] : 0;
        int incl = v;
        #pragma unroll
        for (int off = 1; off < 64; off <<= 1) {
            int t = __shfl_up(incl, off);
            if (lane >= off) incl += t;
        }
        if (lane == 63) wsum[wid] = incl;
        __syncthreads();
        if (wid == 0 && lane < 16) {
            int s = wsum[lane], si = s;
            #pragma unroll
            for (int off = 1; off < 16; off <<= 1) {
                int t = __shfl_up(si, off);
                if (lane >= off) si += t;
            }
            wsum[lane] = si - s;  // exclusive
        }
        __syncthreads();
        int excl = running + wsum[wid] + (incl - v);
        if (i < n) { row_ptr[i] = excl; cursor[i] = excl; }
        __syncthreads();
        if (tid == 1023) running = excl + v;
        __syncthreads();
    }
    if (tid == 0) row_ptr[n] = running;
}

// p = cursor[b[e]]++; col[p] = a[e]
__global__ void fill_kernel(const int* __restrict__ a, const int* __restrict__ b,
                            int* __restrict__ cursor, int* __restrict__ col, int E) {
    int e = blockIdx.x * blockDim.x + threadIdx.x;
    if (e < E) {
        int p = atomicAdd(&cursor[b[e]], 1);
        col[p] = a[e];
    }
}

// deterministic neighbor order for the dst-CSR (float gathers depend on order)
__global__ void sort_rows_kernel(const int* __restrict__ row_ptr, int* __restrict__ col, int n) {
    int v = blockIdx.x * blockDim.x + threadIdx.x;
    if (v >= n) return;
    int e0 = row_ptr[v], e1 = row_ptr[v + 1];
    for (int i = e0 + 1; i < e1; ++i) {
        int key = col[i];
        int j = i - 1;
        while (j >= e0 && col[j] > key) { col[j + 1] = col[j]; --j; }
        col[j + 1] = key;
    }
}

// ---------------- masked degrees (fallback path kernels kept) ----------------
__global__ void out_deg_mask_kernel(const int* __restrict__ src, const int* __restrict__ dst,
                                    const float* __restrict__ m, float* __restrict__ so, int E) {
    int e = blockIdx.x * blockDim.x + threadIdx.x;
    if (e < E) {
        float md = m[dst[e]];
        if (md != 0.f) atomicAdd(&so[src[e]], md);
    }
}

__global__ void in_deg_mask_kernel(const int* __restrict__ row_ptr, const int* __restrict__ col,
                                   const float* __restrict__ m, float* __restrict__ si, int n) {
    int v = blockIdx.x * blockDim.x + threadIdx.x;
    if (v < n) {
        float s = 0.f;
        int e1 = row_ptr[v + 1];
        for (int e = row_ptr[v]; e < e1; ++e) s += m[col[e]];
        si[v] = s;
    }
}

__global__ void scale_full_kernel(const int* __restrict__ dout, const int* __restrict__ din,
                                  float* __restrict__ s, float* __restrict__ t, int n) {
    int v = blockIdx.x * blockDim.x + threadIdx.x;
    if (v < n) {
        s[v] = 1.f / sqrtf((float)max(dout[v], 1));
        t[v] = 1.f / sqrtf((float)max(din[v], 1));
    }
}

__global__ void scale_mask_kernel(const float* __restrict__ gate, const float* __restrict__ mask,
                                  const float* __restrict__ so, const float* __restrict__ si,
                                  float* __restrict__ s, float* __restrict__ t, int n) {
    int v = blockIdx.x * blockDim.x + threadIdx.x;
    if (v < n) {
        s[v] = gate[v] * (1.f / sqrtf(fmaxf(so[v], 1.f)));
        t[v] = mask[v] * (1.f / sqrtf(fmaxf(si[v], 1.f)));
    }
}

// fused masked degrees + scales (sums of 0/1 -> order-exact)
__global__ void deg_scale_kernel(const int* __restrict__ rp_s, const int* __restrict__ cs,
                                 const int* __restrict__ rp_d, const int* __restrict__ cd,
                                 const float* __restrict__ gate, const float* __restrict__ mask,
                                 float* __restrict__ s, float* __restrict__ t,
                                 float* __restrict__ so_out, float* __restrict__ si_out, int n) {
    int v = blockIdx.x * blockDim.x + threadIdx.x;
    if (v >= n) return;
    float so = 0.f;
    int e1 = rp_s[v + 1];
    for (int e = rp_s[v]; e < e1; ++e) so += mask[cs[e]];
    float si = 0.f;
    e1 = rp_d[v + 1];
    for (int e = rp_d[v]; e < e1; ++e) si += mask[cd[e]];
    s[v] = gate[v] * (1.f / sqrtf(fmaxf(so, 1.f)));
    t[v] = mask[v] * (1.f / sqrtf(fmaxf(si, 1.f)));
    so_out[v] = so;
    si_out[v] = si;
}

// ---------------- aggregation from f32 FEATURES, F=128 (full graph) ----------------
__global__ void agg_feat_128_kernel(const int* __restrict__ row_ptr, const int* __restrict__ col,
                                    const float* __restrict__ X, const float* __restrict__ s,
                                    const float* __restrict__ t, float* __restrict__ out, int n) {
    int tid = threadIdx.x;
    int node = blockIdx.x * 8 + (tid >> 5);
    int f4 = tid & 31;
    if (node >= n) return;
    int e0 = row_ptr[node], e1 = row_ptr[node + 1];
    const float4* X4 = (const float4*)X;
    float ax = 0.f, ay = 0.f, az = 0.f, aw = 0.f;
    int e = e0;
    for (; e + 3 < e1; e += 4) {
        int u0 = col[e], u1 = col[e + 1], u2 = col[e + 2], u3 = col[e + 3];
        float s0 = s[u0], s1 = s[u1], s2 = s[u2], s3 = s[u3];
        float4 x0 = X4[(size_t)u0 * 32 + f4];
        float4 x1 = X4[(size_t)u1 * 32 + f4];
        float4 x2 = X4[(size_t)u2 * 32 + f4];
        float4 x3 = X4[(size_t)u3 * 32 + f4];
        ax += s0 * x0.x; ay += s0 * x0.y; az += s0 * x0.z; aw += s0 * x0.w;
        ax += s1 * x1.x; ay += s1 * x1.y; az += s1 * x1.z; aw += s1 * x1.w;
        ax += s2 * x2.x; ay += s2 * x2.y; az += s2 * x2.z; aw += s2 * x2.w;
        ax += s3 * x3.x; ay += s3 * x3.y; az += s3 * x3.z; aw += s3 * x3.w;
    }
    for (; e < e1; ++e) {
        int u = col[e];
        float sc = s[u];
        float4 q = X4[(size_t)u * 32 + f4];
        ax += sc * q.x; ay += sc * q.y; az += sc * q.z; aw += sc * q.w;
    }
    float tv = t[node];
    float4 r; r.x = ax * tv; r.y = ay * tv; r.z = az * tv; r.w = aw * tv;
    ((float4*)out)[(size_t)node * 32 + f4] = r;
}

// ---------------- aggregation over f32 workspace, F=256 ----------------
template <bool MASKED>
__global__ void agg_f32_256_kernel(const int* __restrict__ row_ptr, const int* __restrict__ col,
                                   const float* __restrict__ X, const float* __restrict__ s,
                                   const float* __restrict__ t, float* __restrict__ out, int n) {
    int tid = threadIdx.x;
    int node = blockIdx.x * 4 + (tid >> 6);
    int f4 = tid & 63;
    if (node >= n) return;
    float tv = t[node];
    if (MASKED && tv == 0.f) return;
    int e0 = row_ptr[node], e1 = row_ptr[node + 1];
    const float4* X4 = (const float4*)X;
    float ax = 0.f, ay = 0.f, az = 0.f, aw = 0.f;
    int e = e0;
    for (; e + 3 < e1; e += 4) {
        int u0 = col[e], u1 = col[e + 1], u2 = col[e + 2], u3 = col[e + 3];
        float s0 = s[u0], s1 = s[u1], s2 = s[u2], s3 = s[u3];
        if (!MASKED) {
            float4 x0 = X4[(size_t)u0 * 64 + f4];
            float4 x1 = X4[(size_t)u1 * 64 + f4];
            float4 x2 = X4[(size_t)u2 * 64 + f4];
            float4 x3 = X4[(size_t)u3 * 64 + f4];
            ax += s0 * x0.x; ay += s0 * x0.y; az += s0 * x0.z; aw += s0 * x0.w;
            ax += s1 * x1.x; ay += s1 * x1.y; az += s1 * x1.z; aw += s1 * x1.w;
            ax += s2 * x2.x; ay += s2 * x2.y; az += s2 * x2.z; aw += s2 * x2.w;
            ax += s3 * x3.x; ay += s3 * x3.y; az += s3 * x3.z; aw += s3 * x3.w;
        } else {
            if (s0 != 0.f) { float4 x = X4[(size_t)u0 * 64 + f4];
                ax += s0 * x.x; ay += s0 * x.y; az += s0 * x.z; aw += s0 * x.w; }
            if (s1 != 0.f) { float4 x = X4[(size_t)u1 * 64 + f4];
                ax += s1 * x.x; ay += s1 * x.y; az += s1 * x.z; aw += s1 * x.w; }
            if (s2 != 0.f) { float4 x = X4[(size_t)u2 * 64 + f4];
                ax += s2 * x.x; ay += s2 * x.y; az += s2 * x.z; aw += s2 * x.w; }
            if (s3 != 0.f) { float4 x = X4[(size_t)u3 * 64 + f4];
                ax += s3 * x.x; ay += s3 * x.y; az += s3 * x.z; aw += s3 * x.w; }
        }
    }
    for (; e < e1; ++e) {
        int u = col[e];
        float sc = s[u];
        if (!MASKED || sc != 0.f) {
            float4 xv = X4[(size_t)u * 64 + f4];
            ax += sc * xv.x; ay += sc * xv.y; az += sc * xv.z; aw += sc * xv.w;
        }
    }
    float4 r; r.x = ax * tv; r.y = ay * tv; r.z = az * tv; r.w = aw * tv;
    ((float4*)out)[(size_t)node * 64 + f4] = r;
}

// masked agg over compacted node list (bit-identical per node)
__global__ void agg_rows_256_kernel(const int* __restrict__ row_ptr, const int* __restrict__ col,
                                    const float* __restrict__ X, const float* __restrict__ s,
                                    const float* __restrict__ t, const int* __restrict__ idx,
                                    int Mc, float* __restrict__ out) {
    int tid = threadIdx.x;
    int li = blockIdx.x * 4 + (tid >> 6);
    int f4 = tid & 63;
    if (li >= Mc) return;
    int node = idx[li];
    float tv = t[node];
    int e0 = row_ptr[node], e1 = row_ptr[node + 1];
    const float4* X4 = (const float4*)X;
    float ax = 0.f, ay = 0.f, az = 0.f, aw = 0.f;
    int e = e0;
    for (; e + 3 < e1; e += 4) {
        int u0 = col[e], u1 = col[e + 1], u2 = col[e + 2], u3 = col[e + 3];
        float s0 = s[u0], s1 = s[u1], s2 = s[u2], s3 = s[u3];
        if (s0 != 0.f) { float4 x = X4[(size_t)u0 * 64 + f4];
            ax += s0 * x.x; ay += s0 * x.y; az += s0 * x.z; aw += s0 * x.w; }
        if (s1 != 0.f) { float4 x = X4[(size_t)u1 * 64 + f4];
            ax += s1 * x.x; ay += s1 * x.y; az += s1 * x.z; aw += s1 * x.w; }
        if (s2 != 0.f) { float4 x = X4[(size_t)u2 * 64 + f4];
            ax += s2 * x.x; ay += s2 * x.y; az += s2 * x.z; aw += s2 * x.w; }
        if (s3 != 0.f) { float4 x = X4[(size_t)u3 * 64 + f4];
            ax += s3 * x.x; ay += s3 * x.y; az += s3 * x.z; aw += s3 * x.w; }
    }
    for (; e < e1; ++e) {
        int u = col[e];
        float sc = s[u];
        if (sc != 0.f) {
            float4 xv = X4[(size_t)u * 64 + f4];
            ax += sc * xv.x; ay += sc * xv.y; az += sc * xv.z; aw += sc * xv.w;
        }
    }
    float4 r; r.x = ax * tv; r.y = ay * tv; r.z = az * tv; r.w = aw * tv;
    ((float4*)out)[(size_t)node * 64 + f4] = r;
}

// ---------------- post-GEMM 128-dim gather for dec1 ----------------
__global__ void agg_bias_128_kernel(const int* __restrict__ row_ptr, const int* __restrict__ col,
                                    const float* __restrict__ P, const float* __restrict__ t,
                                    const float* __restrict__ bias, float* __restrict__ out, int n) {
    int tid = threadIdx.x;
    int node = blockIdx.x * 8 + (tid >> 5);
    int f4 = tid & 31;
    if (node >= n) return;
    int e0 = row_ptr[node], e1 = row_ptr[node + 1];
    const float4* P4 = (const float4*)P;
    float ax = 0.f, ay = 0.f, az = 0.f, aw = 0.f;
    int e = e0;
    for (; e + 3 < e1; e += 4) {
        int u0 = col[e], u1 = col[e + 1], u2 = col[e + 2], u3 = col[e + 3];
        float4 x0 = P4[(size_t)u0 * 32 + f4];
        float4 x1 = P4[(size_t)u1 * 32 + f4];
        float4 x2 = P4[(size_t)u2 * 32 + f4];
        float4 x3 = P4[(size_t)u3 * 32 + f4];
        ax += x0.x; ay += x0.y; az += x0.z; aw += x0.w;
        ax += x1.x; ay += x1.y; az += x1.z; aw += x1.w;
        ax += x2.x; ay += x2.y; az += x2.z; aw += x2.w;
        ax += x3.x; ay += x3.y; az += x3.z; aw += x3.w;
    }
    for (; e < e1; ++e) {
        int u = col[e];
        float4 q = P4[(size_t)u * 32 + f4];
        ax += q.x; ay += q.y; az += q.z; aw += q.w;
    }
    float tv = t[node];
    float4 bv = ((const float4*)bias)[f4];
    float4 r;
    r.x = ax * tv + bv.x; r.y = ay * tv + bv.y;
    r.z = az * tv + bv.z; r.w = aw * tv + bv.w;
    ((float4*)out)[(size_t)node * 32 + f4] = r;
}

// ---------------- GEMM (full rows): 64x128 tile, 4x(4+4) micro-tile ----------------
template <bool RELU>
__global__ __launch_bounds__(256) void gemm_kernel(const float* __restrict__ A,
                                                   const float* __restrict__ W,
                                                   const float* __restrict__ bias,
                                                   const float* __restrict__ mask,
                                                   const float* __restrict__ rowscale,
                                                   float* __restrict__ C, int M, int K, int Nn) {
    __shared__ float As[16][68];
    __shared__ float Bs[16][132];
    int tid = threadIdx.x;
    int bm = blockIdx.x * 64, bn = blockIdx.y * 128;
    int mA = tid >> 2, kqA = (tid & 3) * 4;
    int kB = tid >> 4, nqB = (tid & 15) * 8;
    int tm = (tid >> 4) * 4, tn = (tid & 15) * 4;
    float acc[4][8] = {};
    float rs = rowscale ? rowscale[bm + mA] : 1.f;
    for (int k0 = 0; k0 < K; k0 += 16) {
        float4 av = *(const float4*)(A + (size_t)(bm + mA) * K + k0 + kqA);
        As[kqA + 0][mA] = av.x * rs; As[kqA + 1][mA] = av.y * rs;
        As[kqA + 2][mA] = av.z * rs; As[kqA + 3][mA] = av.w * rs;
        const float* wp = W + (size_t)(k0 + kB) * Nn + bn + nqB;
        *(float4*)&Bs[kB][nqB]     = *(const float4*)wp;
        *(float4*)&Bs[kB][nqB + 4] = *(const float4*)(wp + 4);
        __syncthreads();
        #pragma unroll
        for (int kk = 0; kk < 16; ++kk) {
            float4 a  = *(const float4*)&As[kk][tm];
            float4 b0 = *(const float4*)&Bs[kk][tn];
            float4 b1 = *(const float4*)&Bs[kk][tn + 64];
            float ar[4] = {a.x, a.y, a.z, a.w};
            float br[8] = {b0.x, b0.y, b0.z, b0.w, b1.x, b1.y, b1.z, b1.w};
            #pragma unroll
            for (int i2 = 0; i2 < 4; i2++)
                #pragma unroll
                for (int j = 0; j < 8; j++) acc[i2][j] += ar[i2] * br[j];
        }
        __syncthreads();
    }
    #pragma unroll
    for (int i2 = 0; i2 < 4; i2++) {
        int row = bm + tm + i2;
        if (row < M) {
            float mv = mask ? mask[row] : 1.f;
            float o[8];
            #pragma unroll
            for (int j = 0; j < 8; j++) {
                int cj = (j < 4) ? (tn + j) : (64 + tn + j - 4);
                float x = acc[i2][j] + (bias ? bias[bn + cj] : 0.f);
                if (RELU) x = fmaxf(x, 0.f);
                o[j] = x * mv;
            }
            float* cp = C + (size_t)row * Nn + bn;
            *(float4*)(cp + tn)      = make_float4(o[0], o[1], o[2], o[3]);
            *(float4*)(cp + 64 + tn) = make_float4(o[4], o[5], o[6], o[7]);
        }
    }
}

// ---------------- GEMM over compacted row list ----------------
template <bool RELU>
__global__ __launch_bounds__(256) void gemm_rows_kernel(const float* __restrict__ A,
                                                        const float* __restrict__ W,
                                                        const float* __restrict__ bias,
                                                        const int* __restrict__ idx, int Mc,
                                                        float* __restrict__ C, int K, int Nn) {
    __shared__ float As[16][68];
    __shared__ float Bs[16][132];
    __shared__ int ridx[64];
    int tid = threadIdx.x;
    int bm = blockIdx.x * 64, bn = blockIdx.y * 128;
    if (tid < 64) {
        int r = bm + tid;
        ridx[tid] = (r < Mc) ? idx[r] : idx[0];
    }
    __syncthreads();
    int mA = tid >> 2, kqA = (tid & 3) * 4;
    int kB = tid >> 4, nqB = (tid & 15) * 8;
    int tm = (tid >> 4) * 4, tn = (tid & 15) * 4;
    int rA = ridx[mA];
    float acc[4][8] = {};
    for (int k0 = 0; k0 < K; k0 += 16) {
        float4 av = *(const float4*)(A + (size_t)rA * K + k0 + kqA);
        As[kqA + 0][mA] = av.x; As[kqA + 1][mA] = av.y;
        As[kqA + 2][mA] = av.z; As[kqA + 3][mA] = av.w;
        const float* wp = W + (size_t)(k0 + kB) * Nn + bn + nqB;
        *(float4*)&Bs[kB][nqB]     = *(const float4*)wp;
        *(float4*)&Bs[kB][nqB + 4] = *(const float4*)(wp + 4);
        __syncthreads();
        #pragma unroll
        for (int kk = 0; kk < 16; ++kk) {
            float4 a  = *(const float4*)&As[kk][tm];
            float4 b0 = *(const float4*)&Bs[kk][tn];
            float4 b1 = *(const float4*)&Bs[kk][tn + 64];
            float ar[4] = {a.x, a.y, a.z, a.w};
            float br[8] = {b0.x, b0.y, b0.z, b0.w, b1.x, b1.y, b1.z, b1.w};
            #pragma unroll
            for (int i2 = 0; i2 < 4; i2++)
                #pragma unroll
                for (int j = 0; j < 8; j++) acc[i2][j] += ar[i2] * br[j];
        }
        __syncthreads();
    }
    #pragma unroll
    for (int i2 = 0; i2 < 4; i2++) {
        int r = bm + tm + i2;
        if (r < Mc) {
            int row = ridx[tm + i2];
            float o[8];
            #pragma unroll
            for (int j = 0; j < 8; j++) {
                int cj = (j < 4) ? (tn + j) : (64 + tn + j - 4);
                float x = acc[i2][j] + bias[bn + cj];
                if (RELU) x = fmaxf(x, 0.f);
                o[j] = x;
            }
            float* cp = C + (size_t)row * Nn + bn;
            *(float4*)(cp + tn)      = make_float4(o[0], o[1], o[2], o[3]);
            *(float4*)(cp + 64 + tn) = make_float4(o[4], o[5], o[6], o[7]);
        }
    }
}

// ---------------- pooling score ----------------
__global__ void score_kernel(const float* __restrict__ H, const float* __restrict__ Wp,
                             const float* __restrict__ bp, const float* __restrict__ mask,
                             float* __restrict__ scores, float* __restrict__ keys, int n) {
    int lane = threadIdx.x & 63;
    int node = blockIdx.x * 4 + (threadIdx.x >> 6);
    if (node >= n) return;
    float4 hv = ((const float4*)(H + (size_t)node * 256))[lane];
    float4 wq = ((const float4*)Wp)[lane];
    float d = hv.x * wq.x + hv.y * wq.y + hv.z * wq.z + hv.w * wq.w;
    #pragma unroll
    for (int off = 32; off > 0; off >>= 1) d += __shfl_down(d, off);
    if (lane == 0) {
        float sc = 1.f / (1.f + expf(-(d + bp[0])));
        scores[node] = sc;
        keys[node] = (mask && mask[node] == 0.f) ? -1e9f : sc;
    }
}

// ---------------- top-K selection ----------------
__device__ __forceinline__ unsigned key_u(float f) {
    unsigned u = __float_as_uint(f);
    return (u & 0x80000000u) ? ~u : (u | 0x80000000u);
}

__device__ __forceinline__ void wave_hist_add(int* __restrict__ hist, unsigned bin, bool valid) {
    int lane = threadIdx.x & 63;
    while (true) {
        unsigned long long vmask = __ballot(valid);
        if (vmask == 0ull) break;
        int leader = __ffsll((long long)vmask) - 1;
        unsigned lbin = (unsigned)__shfl((int)bin, leader);
        bool match = valid && (bin == lbin);
        unsigned long long mmask = __ballot(match);
        if (lane == leader) atomicAdd(&hist[lbin], __popcll(mmask));
        if (match) valid = false;
    }
}

// Wave-aggregated list append (R15 fix for the R14 atomic-serialization
// regression: leader does ONE atomicAdd per wave, lanes write base+rank).
__device__ __forceinline__ void wave_append(int* __restrict__ cnt, int* __restrict__ list,
                                            bool pred, int val) {
    int lane = threadIdx.x & 63;
    unsigned long long m = __ballot(pred);
    if (m == 0ull) return;
    int leader = __ffsll((long long)m) - 1;
    int base = 0;
    if (lane == leader) base = atomicAdd(cnt, __popcll(m));
    base = __shfl(base, leader);
    if (pred) list[base + __popcll(m & ((1ull << lane) - 1ull))] = val;
}

// -------- fallback: single block radix select --------
__global__ void topk_kernel(const float* __restrict__ keys, const float* __restrict__ scores,
                            float* __restrict__ nm, float* __restrict__ gate, int n, int K) {
    __shared__ int hist[256];
    __shared__ unsigned sh_prefix;
    __shared__ int sh_krem;
    __shared__ int sh_running;
    __shared__ int wsum[16];
    int tid = threadIdx.x, lane = tid & 63, wid = tid >> 6;
    if (tid == 0) { sh_prefix = 0u; sh_krem = K; sh_running = 0; }
    __syncthreads();
    for (int pass = 0; pass < 4; ++pass) {
        int shift = 24 - pass * 8;
        if (tid < 256) hist[tid] = 0;
        __syncthreads();
        unsigned pmask = (pass == 0) ? 0u : (0xFFFFFFFFu << (shift + 8));
        unsigned prefix = sh_prefix;
        for (int i = tid; i < n; i += 1024) {
            unsigned u = key_u(keys[i]);
            if ((u & pmask) == prefix) atomicAdd(&hist[(u >> shift) & 0xFF], 1);
        }
        __syncthreads();
        if (tid == 0) {
            int krem = sh_krem;
            int b;
            for (b = 255; b > 0; --b) {
                int c = hist[b];
                if (c >= krem) break;
                krem -= c;
            }
            sh_prefix = prefix | ((unsigned)b << shift);
            sh_krem = krem;
        }
        __syncthreads();
    }
    unsigned Tkey = sh_prefix;
    int need_eq = sh_krem;
    for (int base = 0; base < n; base += 1024) {
        int i = base + tid;
        unsigned u = 0; int flagv = 0;
        if (i < n) { u = key_u(keys[i]); flagv = (u == Tkey) ? 1 : 0; }
        unsigned long long bal = __ballot(flagv);
        int rank_w = __popcll(bal & ((1ull << lane) - 1ull));
        if (lane == 63) wsum[wid] = __popcll(bal);
        __syncthreads();
        int woff = 0;
        for (int w = 0; w < wid; ++w) woff += wsum[w];
        int grank = sh_running + woff + rank_w;
        if (i < n) {
            float v = (u > Tkey) ? 1.f : ((flagv && grank < need_eq) ? 1.f : 0.f);
            nm[i] = v;
            gate[i] = v * scores[i];
        }
        __syncthreads();
        if (tid == 0) {
            int tot = 0;
            for (int w = 0; w < 16; ++w) tot += wsum[w];
            sh_running += tot;
        }
        __syncthreads();
    }
}

// -------- fast path: grid-wide radix select, 2 passes of 16 bits --------
__global__ void topk_hist1(const float* __restrict__ keys, int n, int* __restrict__ hist) {
    int i = blockIdx.x * blockDim.x + threadIdx.x;
    unsigned bin = 0; bool valid = (i < n);
    if (valid) bin = key_u(keys[i]) >> 16;
    wave_hist_add(hist, bin, valid);
}

// scan1: finds threshold bucket; zeroes its own bins afterward (race-free).
__global__ void topk_scan1(int* __restrict__ hist, int K, int* __restrict__ sel) {
    __shared__ int arr[1024];
    int tid = threadIdx.x;
    int base = tid * 64;
    int local = 0;
    #pragma unroll 8
    for (int b = 0; b < 64; ++b) local += hist[base + b];
    arr[tid] = local;
    __syncthreads();
    for (int off = 1; off < 1024; off <<= 1) {
        int v = (tid + off < 1024) ? arr[tid + off] : 0;
        __syncthreads();
        arr[tid] += v;
        __syncthreads();
    }
    int above = arr[tid] - local;
    if (above < K && arr[tid] >= K) {
        int run = above;
        for (int b = base + 63; b >= base; --b) {
            int c = hist[b];
            if (run + c >= K) { sel[0] = b; sel[1] = K - run; break; }
            run += c;
        }
    }
    #pragma unroll 8
    for (int b = 0; b < 64; ++b) hist[base + b] = 0;
}

__global__ void topk_hist2(const float* __restrict__ keys, int n, const int* __restrict__ sel,
                           int* __restrict__ hist) {
    int i = blockIdx.x * blockDim.x + threadIdx.x;
    unsigned bin = 0; bool valid = false;
    if (i < n) {
        unsigned u = key_u(keys[i]);
        if ((int)(u >> 16) == sel[0]) { bin = u & 0xFFFF; valid = true; }
    }
    wave_hist_add(hist, bin, valid);
}

// scan2: finds Tkey/need_eq, zeroes bins, resets tie + compaction counters.
__global__ void topk_scan2(int* __restrict__ hist, int* __restrict__ sel,
                           int* __restrict__ tie_cnt, int* __restrict__ ccnt) {
    __shared__ int arr[1024];
    int tid = threadIdx.x;
    if (tid == 0) { *tie_cnt = 0; *ccnt = 0; }
    int K = sel[1];
    int base = tid * 64;
    int local = 0;
    #pragma unroll 8
    for (int b = 0; b < 64; ++b) local += hist[base + b];
    arr[tid] = local;
    __syncthreads();
    for (int off = 1; off < 1024; off <<= 1) {
        int v = (tid + off < 1024) ? arr[tid + off] : 0;
        __syncthreads();
        arr[tid] += v;
        __syncthreads();
    }
    int above = arr[tid] - local;
    if (above < K && arr[tid] >= K) {
        int run = above;
        for (int b = base + 63; b >= base; --b) {
            int c = hist[b];
            if (run + c >= K) {
                sel[2] = (int)((((unsigned)sel[0]) << 16) | (unsigned)b);
                sel[3] = K - run;
                break;
            }
            run += c;
        }
    }
    #pragma unroll 8
    for (int b = 0; b < 64; ++b) hist[base + b] = 0;
}

// mark: writes nm/gate; wave-aggregated appends to selected + tie lists.
__global__ void topk_mark(const float* __restrict__ keys, const float* __restrict__ scores,
                          const int* __restrict__ sel, float* __restrict__ nm,
                          float* __restrict__ gate, int* __restrict__ tie_list,
                          int* __restrict__ tie_cnt, int* __restrict__ sidx,
                          int* __restrict__ ccnt, int n) {
    int i = blockIdx.x * blockDim.x + threadIdx.x;
    unsigned Tkey = (unsigned)sel[2];
    bool in = (i < n);
    bool selp = false, tiep = false;
    if (in) {
        unsigned u = key_u(keys[i]);
        selp = (u > Tkey);
        tiep = (u == Tkey);
        float v = selp ? 1.f : 0.f;
        nm[i] = v;
        gate[i] = v * scores[i];
    }
    wave_append(ccnt, sidx, selp, i);
    wave_append(tie_cnt, tie_list, tiep, i);
}

__global__ void topk_ties(const float* __restrict__ scores, const int* __restrict__ sel,
                          const int* __restrict__ tie_list, const int* __restrict__ tie_cnt,
                          float* __restrict__ nm, float* __restrict__ gate,
                          int* __restrict__ sidx, int* __restrict__ ccnt) {
    int cnt = *tie_cnt;
    int need = sel[3];
    for (int j = threadIdx.x; j < cnt; j += blockDim.x) {
        int idx = tie_list[j];
        int rank = 0;
        for (int k2 = 0; k2 < cnt; ++k2) rank += (tie_list[k2] < idx) ? 1 : 0;
        if (rank < need) {
            nm[idx] = 1.f; gate[idx] = scores[idx];
            int p = atomicAdd(ccnt, 1); sidx[p] = idx;   // tie count tiny
        }
    }
}

// ---------------- adds ----------------
__global__ void add_mask_kernel(float* __restrict__ A, const float* __restrict__ B,
                                const float* __restrict__ mask, int n4) {
    int i = blockIdx.x * blockDim.x + threadIdx.x;
    if (i < n4) {
        float4 a = ((float4*)A)[i];
        float4 b = ((const float4*)B)[i];
        if (mask && mask[i >> 6] == 0.f) { a.x = 0.f; a.y = 0.f; a.z = 0.f; a.w = 0.f; }
        a.x += b.x; a.y += b.y; a.z += b.z; a.w += b.w;
        ((float4*)A)[i] = a;
    }
}

extern "C" void kernel_launch(void* const* d_in, const int* in_sizes, int n_in,
                              void* d_out, int out_size, void* d_ws, size_t ws_size,
                              hipStream_t stream) {
    const int n = in_sizes[0] / 128;   // 50000
    const int E = in_sizes[1];         // 800000
    const int NPAD = ((n + 63) / 64) * 64;
    const int K1 = 25000, K2 = 12500;

    const float* features = (const float*)d_in[0];
    const int* src = (const int*)d_in[1];
    const int* dst = (const int*)d_in[2];
    const float* W_embed = (const float*)d_in[3];
    const float* b_embed = (const float*)d_in[4];
    const float* W_enc0  = (const float*)d_in[5];
    const float* b_enc0  = (const float*)d_in[6];
    const float* W_enc1  = (const float*)d_in[7];
    const float* b_enc1  = (const float*)d_in[8];
    const float* W_p0    = (const float*)d_in[9];
    const float* b_p0    = (const float*)d_in[10];
    const float* W_p1    = (const float*)d_in[11];
    const float* b_p1    = (const float*)d_in[12];
    const float* W_bot   = (const float*)d_in[13];
    const float* b_bot   = (const float*)d_in[14];
    const float* W_dec0  = (const float*)d_in[15];
    const float* b_dec0  = (const float*)d_in[16];
    const float* W_dec1  = (const float*)d_in[17];
    const float* b_dec1  = (const float*)d_in[18];
    float* out_f = (float*)d_out;

    char* ws = (char*)d_ws;
    size_t off = 0;
    auto alloc = [&](size_t bytes) -> void* {
        void* p = ws + off;
        off += (bytes + 255) & ~(size_t)255;
        return p;
    };
    (void)alloc(256);  // pad
    int* row_ptr  = (int*)alloc((size_t)(n + 1) * 4);
    int* cursor   = (int*)alloc((size_t)n * 4);
    int* col      = (int*)alloc((size_t)E * 4);
    int* deg_out_i= (int*)alloc((size_t)n * 4);
    int* deg_in_i = (int*)alloc((size_t)n * 4);
    float* so_m1  = (float*)alloc((size_t)n * 4);
    float* si_m1  = (float*)alloc((size_t)n * 4);
    float* so_m2  = (float*)alloc((size_t)n * 4);
    float* si_m2  = (float*)alloc((size_t)n * 4);
    float* sarr   = (float*)alloc((size_t)n * 4);
    float* tarr   = (float*)alloc((size_t)n * 4);
    float* scores1= (float*)alloc((size_t)n * 4);
    float* keys1  = (float*)alloc((size_t)n * 4);
    float* scores2= (float*)alloc((size_t)n * 4);
    float* keys2  = (float*)alloc((size_t)n * 4);
    float* nm1    = (float*)alloc((size_t)n * 4);
    float* gate1  = (float*)alloc((size_t)n * 4);
    float* nm2    = (float*)alloc((size_t)n * 4);
    float* gate2  = (float*)alloc((size_t)n * 4);
    size_t big = (size_t)NPAD * 256 * 4;
    float* A = (float*)alloc(big);
    float* B = (float*)alloc(big);
    float* C = (float*)alloc(big);
    float* D = (float*)alloc(big);
    // ---- tail ----
    int* rhist    = (int*)alloc(65536 * 4);
    int* sel      = (int*)alloc(256);
    int* tie_cnt  = (int*)alloc(256);
    int* tie_list = (int*)alloc((size_t)n * 4);
    float* s0     = (float*)alloc((size_t)n * 4);
    float* t0     = (float*)alloc((size_t)n * 4);
    int* idx1     = (int*)alloc((size_t)n * 4);
    int* idx2     = (int*)alloc((size_t)n * 4);
    int* ccnt     = (int*)alloc(256);
    int* row_ptr_s= (int*)alloc((size_t)(n + 1) * 4);
    int* cursor_s = (int*)alloc((size_t)n * 4);
    int* col_s    = (int*)alloc((size_t)E * 4);
    bool fast = (off <= ws_size);

    dim3 blk(256);
    int gE = (E + 255) / 256;
    int gN = (n + 255) / 256;
    int gAgg256 = (n + 3) / 4;
    int gAgg128 = (n + 7) / 8;
    int gAggK1 = (K1 + 3) / 4;
    int gAggK2 = (K2 + 3) / 4;
    int gScore = (n + 3) / 4;
    dim3 gemm_g(NPAD / 64, 2);
    dim3 gemm_g128(NPAD / 64, 1);
    dim3 gemm_gK1((K1 + 63) / 64, 2);
    dim3 gemm_gK2((K2 + 63) / 64, 2);
    int gAdd = (n * 64 + 255) / 256;

    auto run_topk = [&](const float* keys, const float* scores, float* nm, float* gate,
                        int K, int* sidx, int* cc) {
        if (fast) {
            topk_hist1<<<gN, blk, 0, stream>>>(keys, n, rhist);
            topk_scan1<<<1, 1024, 0, stream>>>(rhist, K, sel);
            topk_hist2<<<gN, blk, 0, stream>>>(keys, n, sel, rhist);
            topk_scan2<<<1, 1024, 0, stream>>>(rhist, sel, tie_cnt, cc);
            topk_mark<<<gN, blk, 0, stream>>>(keys, scores, sel, nm, gate, tie_list, tie_cnt,
                                              sidx, cc, n);
            topk_ties<<<1, 256, 0, stream>>>(scores, sel, tie_list, tie_cnt, nm, gate, sidx, cc);
        } else {
            topk_kernel<<<1, 1024, 0, stream>>>(keys, scores, nm, gate, n, K);
        }
    };
    float* sF = fast ? s0 : sarr;
    float* tF = fast ? t0 : tarr;

    // ---- CSR build (dst-CSR sorted; src-CSR unsorted: exact 0/1 sums only) ----
    hipMemsetAsync(deg_out_i, 0, (size_t)n * 4, stream);
    hipMemsetAsync(deg_in_i, 0, (size_t)n * 4, stream);
    if (fast) hipMemsetAsync(rhist, 0, 65536 * 4, stream);   // scans re-zero afterward
    hist_kernel<<<gE, blk, 0, stream>>>(src, dst, deg_out_i, deg_in_i, E);
    scan_kernel<<<1, 1024, 0, stream>>>(deg_in_i, row_ptr, cursor, n);
    fill_kernel<<<gE, blk, 0, stream>>>(src, dst, cursor, col, E);
    sort_rows_kernel<<<gN, blk, 0, stream>>>(row_ptr, col, n);
    if (fast) {
        scan_kernel<<<1, 1024, 0, stream>>>(deg_out_i, row_ptr_s, cursor_s, n);
        fill_kernel<<<gE, blk, 0, stream>>>(dst, src, cursor_s, col_s, E);
    }

    // ---- full-graph degree scales ----
    scale_full_kernel<<<gN, blk, 0, stream>>>(deg_out_i, deg_in_i, sF, tF, n);

    // ---- embed GCN (full graph) -> A ----
    agg_feat_128_kernel<<<gAgg128, blk, 0, stream>>>(row_ptr, col, features, sF, tF, D, n);
    gemm_kernel<true><<<gemm_g, blk, 0, stream>>>(D, W_embed, b_embed, nullptr, nullptr, A, n, 128, 256);

    // ---- enc0 (full graph); hidden0 = B ----
    agg_f32_256_kernel<false><<<gAgg256, blk, 0, stream>>>(row_ptr, col, A, sF, tF, D, n);
    gemm_kernel<true><<<gemm_g, blk, 0, stream>>>(D, W_enc0, b_enc0, nullptr, nullptr, B, n, 256, 256);

    // ---- pool0 ----
    score_kernel<<<gScore, blk, 0, stream>>>(B, W_p0, b_p0, nullptr, scores1, keys1, n);
    run_topk(keys1, scores1, nm1, gate1, K1, idx1, ccnt);

    // ---- enc1 (mask m1, gated input); hidden1 = C ----
    if (fast) {
        deg_scale_kernel<<<gN, blk, 0, stream>>>(row_ptr_s, col_s, row_ptr, col, gate1, nm1,
                                                 sarr, tarr, so_m1, si_m1, n);
        agg_rows_256_kernel<<<gAggK1, blk, 0, stream>>>(row_ptr, col, B, sarr, tarr, idx1, K1, D);
        gemm_rows_kernel<true><<<gemm_gK1, blk, 0, stream>>>(D, W_enc1, b_enc1, idx1, K1, C, 256, 256);
    } else {
        hipMemsetAsync(so_m1, 0, (size_t)n * 4, stream);
        out_deg_mask_kernel<<<gE, blk, 0, stream>>>(src, dst, nm1, so_m1, E);
        in_deg_mask_kernel<<<gN, blk, 0, stream>>>(row_ptr, col, nm1, si_m1, n);
        scale_mask_kernel<<<gN, blk, 0, stream>>>(gate1, nm1, so_m1, si_m1, sarr, tarr, n);
        agg_f32_256_kernel<true><<<gAgg256, blk, 0, stream>>>(row_ptr, col, B, sarr, tarr, D, n);
        gemm_kernel<true><<<gemm_g, blk, 0, stream>>>(D, W_enc1, b_enc1, nm1, nullptr, C, n, 256, 256);
    }

    // ---- pool1 ----
    score_kernel<<<gScore, blk, 0, stream>>>(C, W_p1, b_p1, nm1, scores2, keys2, n);
    run_topk(keys2, scores2, nm2, gate2, K2, idx2, ccnt + 1);

    // ---- bottleneck (mask m2, gated input) -> A ----
    if (fast) {
        deg_scale_kernel<<<gN, blk, 0, stream>>>(row_ptr_s, col_s, row_ptr, col, gate2, nm2,
                                                 sarr, tarr, so_m2, si_m2, n);
        agg_rows_256_kernel<<<gAggK2, blk, 0, stream>>>(row_ptr, col, C, sarr, tarr, idx2, K2, D);
        gemm_rows_kernel<true><<<gemm_gK2, blk, 0, stream>>>(D, W_bot, b_bot, idx2, K2, A, 256, 256);
    } else {
        hipMemsetAsync(so_m2, 0, (size_t)n * 4, stream);
        out_deg_mask_kernel<<<gE, blk, 0, stream>>>(src, dst, nm2, so_m2, E);
        in_deg_mask_kernel<<<gN, blk, 0, stream>>>(row_ptr, col, nm2, si_m2, n);
        scale_mask_kernel<<<gN, blk, 0, stream>>>(gate2, nm2, so_m2, si_m2, sarr, tarr, n);
        agg_f32_256_kernel<true><<<gAgg256, blk, 0, stream>>>(row_ptr, col, C, sarr, tarr, D, n);
        gemm_kernel<true><<<gemm_g, blk, 0, stream>>>(D, W_bot, b_bot, nm2, nullptr, A, n, 256, 256);
    }

    // ---- dec0: h = (m2? bot : 0) + hidden1, GCN mask m1 -> A ----
    add_mask_kernel<<<gAdd, blk, 0, stream>>>(A, C, fast ? nm2 : nullptr, n * 64);
    scale_mask_kernel<<<gN, blk, 0, stream>>>(nm1, nm1, so_m1, si_m1, sarr, tarr, n);
    if (fast) {
        agg_rows_256_kernel<<<gAggK1, blk, 0, stream>>>(row_ptr, col, A, sarr, tarr, idx1, K1, D);
        gemm_rows_kernel<true><<<gemm_gK1, blk, 0, stream>>>(D, W_dec0, b_dec0, idx1, K1, A, 256, 256);
    } else {
        agg_f32_256_kernel<true><<<gAgg256, blk, 0, stream>>>(row_ptr, col, A, sarr, tarr, D, n);
        gemm_kernel<true><<<gemm_g, blk, 0, stream>>>(D, W_dec0, b_dec0, nm1, nullptr, A, n, 256, 256);
    }

    // ---- dec1 (reordered, final layer) ----
    add_mask_kernel<<<gAdd, blk, 0, stream>>>(A, B, fast ? nm1 : nullptr, n * 64);
    if (!fast)
        scale_full_kernel<<<gN, blk, 0, stream>>>(deg_out_i, deg_in_i, sarr, tarr, n);
    gemm_kernel<false><<<gemm_g128, blk, 0, stream>>>(A, W_dec1, nullptr, nullptr, sF, C, n, 256, 128);
    agg_bias_128_kernel<<<gAgg128, blk, 0, stream>>>(row_ptr, col, C, tF, b_dec1, out_f, n);

    (void)n_in; (void)out_size;
}

// Round 16
// 1339.818 us; speedup vs baseline: 1.3378x; 1.0404x over previous
//
#include <hip/hip_runtime.h>
#include <hip/hip_bf16.h>
#include <type_traits>

// ---------------- CSR build ----------------
__global__ void hist_kernel(const int* __restrict__ src, const int* __restrict__ dst,
                            int* __restrict__ deg_out, int* __restrict__ deg_in, int E) {
    int e = blockIdx.x * blockDim.x + threadIdx.x;
    if (e < E) {
        atomicAdd(&deg_out[src[e]], 1);
        atomicAdd(&deg_in[dst[e]], 1);
    }
}

__global__ void scan_kernel(const int* __restrict__ deg, int* __restrict__ row_ptr,
                            int* __restrict__ cursor, int n) {
    __shared__ int wsum[16];
    __shared__ int running;
    int tid = threadIdx.x, lane = tid & 63, wid = tid >> 6;
    if (tid == 0) running = 0;
    __syncthreads();
    for (int base = 0; base < n; base += 1024) {
        int i = base + tid;
        int v = (i < n) ? deg[i] : 0;
        int incl = v;
        #pragma unroll
        for (int off = 1; off < 64; off <<= 1) {
            int t = __shfl_up(incl, off);
            if (lane >= off) incl += t;
        }
        if (lane == 63) wsum[wid] = incl;
        __syncthreads();
        if (wid == 0 && lane < 16) {
            int s = wsum[lane], si = s;
            #pragma unroll
            for (int off = 1; off < 16; off <<= 1) {
                int t = __shfl_up(si, off);
                if (lane >= off) si += t;
            }
            wsum[lane] = si - s;  // exclusive
        }
        __syncthreads();
        int excl = running + wsum[wid] + (incl - v);
        if (i < n) { row_ptr[i] = excl; cursor[i] = excl; }
        __syncthreads();
        if (tid == 1023) running = excl + v;
        __syncthreads();
    }
    if (tid == 0) row_ptr[n] = running;
}

__global__ void fill_kernel(const int* __restrict__ a, const int* __restrict__ b,
                            int* __restrict__ cursor, int* __restrict__ col, int E) {
    int e = blockIdx.x * blockDim.x + threadIdx.x;
    if (e < E) {
        int p = atomicAdd(&cursor[b[e]], 1);
        col[p] = a[e];
    }
}

// deterministic neighbor order (float gathers depend on order)
__global__ void sort_rows_kernel(const int* __restrict__ row_ptr, int* __restrict__ col, int n) {
    int v = blockIdx.x * blockDim.x + threadIdx.x;
    if (v >= n) return;
    int e0 = row_ptr[v], e1 = row_ptr[v + 1];
    for (int i = e0 + 1; i < e1; ++i) {
        int key = col[i];
        int j = i - 1;
        while (j >= e0 && col[j] > key) { col[j + 1] = col[j]; --j; }
        col[j + 1] = key;
    }
}

// ---------------- masked degrees (R13 path: proven cheapest) ----------------
__global__ void out_deg_mask_kernel(const int* __restrict__ src, const int* __restrict__ dst,
                                    const float* __restrict__ m, float* __restrict__ so, int E) {
    int e = blockIdx.x * blockDim.x + threadIdx.x;
    if (e < E) {
        float md = m[dst[e]];
        if (md != 0.f) atomicAdd(&so[src[e]], md);
    }
}

__global__ void in_deg_mask_kernel(const int* __restrict__ row_ptr, const int* __restrict__ col,
                                   const float* __restrict__ m, float* __restrict__ si, int n) {
    int v = blockIdx.x * blockDim.x + threadIdx.x;
    if (v < n) {
        float s = 0.f;
        int e1 = row_ptr[v + 1];
        for (int e = row_ptr[v]; e < e1; ++e) s += m[col[e]];
        si[v] = s;
    }
}

__global__ void scale_full_kernel(const int* __restrict__ dout, const int* __restrict__ din,
                                  float* __restrict__ s, float* __restrict__ t, int n) {
    int v = blockIdx.x * blockDim.x + threadIdx.x;
    if (v < n) {
        s[v] = 1.f / sqrtf((float)max(dout[v], 1));
        t[v] = 1.f / sqrtf((float)max(din[v], 1));
    }
}

__global__ void scale_mask_kernel(const float* __restrict__ gate, const float* __restrict__ mask,
                                  const float* __restrict__ so, const float* __restrict__ si,
                                  float* __restrict__ s, float* __restrict__ t, int n) {
    int v = blockIdx.x * blockDim.x + threadIdx.x;
    if (v < n) {
        s[v] = gate[v] * (1.f / sqrtf(fmaxf(so[v], 1.f)));
        t[v] = mask[v] * (1.f / sqrtf(fmaxf(si[v], 1.f)));
    }
}

// ---------------- aggregation from f32 FEATURES, F=128 (full graph) ----------------
__global__ void agg_feat_128_kernel(const int* __restrict__ row_ptr, const int* __restrict__ col,
                                    const float* __restrict__ X, const float* __restrict__ s,
                                    const float* __restrict__ t, float* __restrict__ out, int n) {
    int tid = threadIdx.x;
    int node = blockIdx.x * 8 + (tid >> 5);
    int f4 = tid & 31;
    if (node >= n) return;
    int e0 = row_ptr[node], e1 = row_ptr[node + 1];
    const float4* X4 = (const float4*)X;
    float ax = 0.f, ay = 0.f, az = 0.f, aw = 0.f;
    int e = e0;
    for (; e + 3 < e1; e += 4) {
        int u0 = col[e], u1 = col[e + 1], u2 = col[e + 2], u3 = col[e + 3];
        float s0 = s[u0], s1 = s[u1], s2 = s[u2], s3 = s[u3];
        float4 x0 = X4[(size_t)u0 * 32 + f4];
        float4 x1 = X4[(size_t)u1 * 32 + f4];
        float4 x2 = X4[(size_t)u2 * 32 + f4];
        float4 x3 = X4[(size_t)u3 * 32 + f4];
        ax += s0 * x0.x; ay += s0 * x0.y; az += s0 * x0.z; aw += s0 * x0.w;
        ax += s1 * x1.x; ay += s1 * x1.y; az += s1 * x1.z; aw += s1 * x1.w;
        ax += s2 * x2.x; ay += s2 * x2.y; az += s2 * x2.z; aw += s2 * x2.w;
        ax += s3 * x3.x; ay += s3 * x3.y; az += s3 * x3.z; aw += s3 * x3.w;
    }
    for (; e < e1; ++e) {
        int u = col[e];
        float sc = s[u];
        float4 q = X4[(size_t)u * 32 + f4];
        ax += sc * q.x; ay += sc * q.y; az += sc * q.z; aw += sc * q.w;
    }
    float tv = t[node];
    float4 r; r.x = ax * tv; r.y = ay * tv; r.z = az * tv; r.w = aw * tv;
    ((float4*)out)[(size_t)node * 32 + f4] = r;
}

// ---------------- aggregation over f32 workspace, F=256 ----------------
template <bool MASKED>
__global__ void agg_f32_256_kernel(const int* __restrict__ row_ptr, const int* __restrict__ col,
                                   const float* __restrict__ X, const float* __restrict__ s,
                                   const float* __restrict__ t, float* __restrict__ out, int n) {
    int tid = threadIdx.x;
    int node = blockIdx.x * 4 + (tid >> 6);
    int f4 = tid & 63;
    if (node >= n) return;
    float tv = t[node];
    if (MASKED && tv == 0.f) return;
    int e0 = row_ptr[node], e1 = row_ptr[node + 1];
    const float4* X4 = (const float4*)X;
    float ax = 0.f, ay = 0.f, az = 0.f, aw = 0.f;
    int e = e0;
    for (; e + 3 < e1; e += 4) {
        int u0 = col[e], u1 = col[e + 1], u2 = col[e + 2], u3 = col[e + 3];
        float s0 = s[u0], s1 = s[u1], s2 = s[u2], s3 = s[u3];
        if (!MASKED) {
            float4 x0 = X4[(size_t)u0 * 64 + f4];
            float4 x1 = X4[(size_t)u1 * 64 + f4];
            float4 x2 = X4[(size_t)u2 * 64 + f4];
            float4 x3 = X4[(size_t)u3 * 64 + f4];
            ax += s0 * x0.x; ay += s0 * x0.y; az += s0 * x0.z; aw += s0 * x0.w;
            ax += s1 * x1.x; ay += s1 * x1.y; az += s1 * x1.z; aw += s1 * x1.w;
            ax += s2 * x2.x; ay += s2 * x2.y; az += s2 * x2.z; aw += s2 * x2.w;
            ax += s3 * x3.x; ay += s3 * x3.y; az += s3 * x3.z; aw += s3 * x3.w;
        } else {
            if (s0 != 0.f) { float4 x = X4[(size_t)u0 * 64 + f4];
                ax += s0 * x.x; ay += s0 * x.y; az += s0 * x.z; aw += s0 * x.w; }
            if (s1 != 0.f) { float4 x = X4[(size_t)u1 * 64 + f4];
                ax += s1 * x.x; ay += s1 * x.y; az += s1 * x.z; aw += s1 * x.w; }
            if (s2 != 0.f) { float4 x = X4[(size_t)u2 * 64 + f4];
                ax += s2 * x.x; ay += s2 * x.y; az += s2 * x.z; aw += s2 * x.w; }
            if (s3 != 0.f) { float4 x = X4[(size_t)u3 * 64 + f4];
                ax += s3 * x.x; ay += s3 * x.y; az += s3 * x.z; aw += s3 * x.w; }
        }
    }
    for (; e < e1; ++e) {
        int u = col[e];
        float sc = s[u];
        if (!MASKED || sc != 0.f) {
            float4 xv = X4[(size_t)u * 64 + f4];
            ax += sc * xv.x; ay += sc * xv.y; az += sc * xv.z; aw += sc * xv.w;
        }
    }
    float4 r; r.x = ax * tv; r.y = ay * tv; r.z = az * tv; r.w = aw * tv;
    ((float4*)out)[(size_t)node * 64 + f4] = r;
}

// masked agg over compacted node list (bit-identical per node)
__global__ void agg_rows_256_kernel(const int* __restrict__ row_ptr, const int* __restrict__ col,
                                    const float* __restrict__ X, const float* __restrict__ s,
                                    const float* __restrict__ t, const int* __restrict__ idx,
                                    int Mc, float* __restrict__ out) {
    int tid = threadIdx.x;
    int li = blockIdx.x * 4 + (tid >> 6);
    int f4 = tid & 63;
    if (li >= Mc) return;
    int node = idx[li];
    float tv = t[node];
    int e0 = row_ptr[node], e1 = row_ptr[node + 1];
    const float4* X4 = (const float4*)X;
    float ax = 0.f, ay = 0.f, az = 0.f, aw = 0.f;
    int e = e0;
    for (; e + 3 < e1; e += 4) {
        int u0 = col[e], u1 = col[e + 1], u2 = col[e + 2], u3 = col[e + 3];
        float s0 = s[u0], s1 = s[u1], s2 = s[u2], s3 = s[u3];
        if (s0 != 0.f) { float4 x = X4[(size_t)u0 * 64 + f4];
            ax += s0 * x.x; ay += s0 * x.y; az += s0 * x.z; aw += s0 * x.w; }
        if (s1 != 0.f) { float4 x = X4[(size_t)u1 * 64 + f4];
            ax += s1 * x.x; ay += s1 * x.y; az += s1 * x.z; aw += s1 * x.w; }
        if (s2 != 0.f) { float4 x = X4[(size_t)u2 * 64 + f4];
            ax += s2 * x.x; ay += s2 * x.y; az += s2 * x.z; aw += s2 * x.w; }
        if (s3 != 0.f) { float4 x = X4[(size_t)u3 * 64 + f4];
            ax += s3 * x.x; ay += s3 * x.y; az += s3 * x.z; aw += s3 * x.w; }
    }
    for (; e < e1; ++e) {
        int u = col[e];
        float sc = s[u];
        if (sc != 0.f) {
            float4 xv = X4[(size_t)u * 64 + f4];
            ax += sc * xv.x; ay += sc * xv.y; az += sc * xv.z; aw += sc * xv.w;
        }
    }
    float4 r; r.x = ax * tv; r.y = ay * tv; r.z = az * tv; r.w = aw * tv;
    ((float4*)out)[(size_t)node * 64 + f4] = r;
}

// ---------------- post-GEMM 128-dim gather for dec1 ----------------
__global__ void agg_bias_128_kernel(const int* __restrict__ row_ptr, const int* __restrict__ col,
                                    const float* __restrict__ P, const float* __restrict__ t,
                                    const float* __restrict__ bias, float* __restrict__ out, int n) {
    int tid = threadIdx.x;
    int node = blockIdx.x * 8 + (tid >> 5);
    int f4 = tid & 31;
    if (node >= n) return;
    int e0 = row_ptr[node], e1 = row_ptr[node + 1];
    const float4* P4 = (const float4*)P;
    float ax = 0.f, ay = 0.f, az = 0.f, aw = 0.f;
    int e = e0;
    for (; e + 3 < e1; e += 4) {
        int u0 = col[e], u1 = col[e + 1], u2 = col[e + 2], u3 = col[e + 3];
        float4 x0 = P4[(size_t)u0 * 32 + f4];
        float4 x1 = P4[(size_t)u1 * 32 + f4];
        float4 x2 = P4[(size_t)u2 * 32 + f4];
        float4 x3 = P4[(size_t)u3 * 32 + f4];
        ax += x0.x; ay += x0.y; az += x0.z; aw += x0.w;
        ax += x1.x; ay += x1.y; az += x1.z; aw += x1.w;
        ax += x2.x; ay += x2.y; az += x2.z; aw += x2.w;
        ax += x3.x; ay += x3.y; az += x3.z; aw += x3.w;
    }
    for (; e < e1; ++e) {
        int u = col[e];
        float4 q = P4[(size_t)u * 32 + f4];
        ax += q.x; ay += q.y; az += q.z; aw += q.w;
    }
    float tv = t[node];
    float4 bv = ((const float4*)bias)[f4];
    float4 r;
    r.x = ax * tv + bv.x; r.y = ay * tv + bv.y;
    r.z = az * tv + bv.z; r.w = aw * tv + bv.w;
    ((float4*)out)[(size_t)node * 32 + f4] = r;
}

// ---------------- GEMM (full rows): 64x128 tile, 4x(4+4) micro-tile ----------------
template <bool RELU>
__global__ __launch_bounds__(256) void gemm_kernel(const float* __restrict__ A,
                                                   const float* __restrict__ W,
                                                   const float* __restrict__ bias,
                                                   const float* __restrict__ mask,
                                                   const float* __restrict__ rowscale,
                                                   float* __restrict__ C, int M, int K, int Nn) {
    __shared__ float As[16][68];
    __shared__ float Bs[16][132];
    int tid = threadIdx.x;
    int bm = blockIdx.x * 64, bn = blockIdx.y * 128;
    int mA = tid >> 2, kqA = (tid & 3) * 4;
    int kB = tid >> 4, nqB = (tid & 15) * 8;
    int tm = (tid >> 4) * 4, tn = (tid & 15) * 4;
    float acc[4][8] = {};
    float rs = rowscale ? rowscale[bm + mA] : 1.f;
    for (int k0 = 0; k0 < K; k0 += 16) {
        float4 av = *(const float4*)(A + (size_t)(bm + mA) * K + k0 + kqA);
        As[kqA + 0][mA] = av.x * rs; As[kqA + 1][mA] = av.y * rs;
        As[kqA + 2][mA] = av.z * rs; As[kqA + 3][mA] = av.w * rs;
        const float* wp = W + (size_t)(k0 + kB) * Nn + bn + nqB;
        *(float4*)&Bs[kB][nqB]     = *(const float4*)wp;
        *(float4*)&Bs[kB][nqB + 4] = *(const float4*)(wp + 4);
        __syncthreads();
        #pragma unroll
        for (int kk = 0; kk < 16; ++kk) {
            float4 a  = *(const float4*)&As[kk][tm];
            float4 b0 = *(const float4*)&Bs[kk][tn];
            float4 b1 = *(const float4*)&Bs[kk][tn + 64];
            float ar[4] = {a.x, a.y, a.z, a.w};
            float br[8] = {b0.x, b0.y, b0.z, b0.w, b1.x, b1.y, b1.z, b1.w};
            #pragma unroll
            for (int i2 = 0; i2 < 4; i2++)
                #pragma unroll
                for (int j = 0; j < 8; j++) acc[i2][j] += ar[i2] * br[j];
        }
        __syncthreads();
    }
    #pragma unroll
    for (int i2 = 0; i2 < 4; i2++) {
        int row = bm + tm + i2;
        if (row < M) {
            float mv = mask ? mask[row] : 1.f;
            float o[8];
            #pragma unroll
            for (int j = 0; j < 8; j++) {
                int cj = (j < 4) ? (tn + j) : (64 + tn + j - 4);
                float x = acc[i2][j] + (bias ? bias[bn + cj] : 0.f);
                if (RELU) x = fmaxf(x, 0.f);
                o[j] = x * mv;
            }
            float* cp = C + (size_t)row * Nn + bn;
            *(float4*)(cp + tn)      = make_float4(o[0], o[1], o[2], o[3]);
            *(float4*)(cp + 64 + tn) = make_float4(o[4], o[5], o[6], o[7]);
        }
    }
}

// ---------------- GEMM over compacted row list ----------------
template <bool RELU>
__global__ __launch_bounds__(256) void gemm_rows_kernel(const float* __restrict__ A,
                                                        const float* __restrict__ W,
                                                        const float* __restrict__ bias,
                                                        const int* __restrict__ idx, int Mc,
                                                        float* __restrict__ C, int K, int Nn) {
    __shared__ float As[16][68];
    __shared__ float Bs[16][132];
    __shared__ int ridx[64];
    int tid = threadIdx.x;
    int bm = blockIdx.x * 64, bn = blockIdx.y * 128;
    if (tid < 64) {
        int r = bm + tid;
        ridx[tid] = (r < Mc) ? idx[r] : idx[0];
    }
    __syncthreads();
    int mA = tid >> 2, kqA = (tid & 3) * 4;
    int kB = tid >> 4, nqB = (tid & 15) * 8;
    int tm = (tid >> 4) * 4, tn = (tid & 15) * 4;
    int rA = ridx[mA];
    float acc[4][8] = {};
    for (int k0 = 0; k0 < K; k0 += 16) {
        float4 av = *(const float4*)(A + (size_t)rA * K + k0 + kqA);
        As[kqA + 0][mA] = av.x; As[kqA + 1][mA] = av.y;
        As[kqA + 2][mA] = av.z; As[kqA + 3][mA] = av.w;
        const float* wp = W + (size_t)(k0 + kB) * Nn + bn + nqB;
        *(float4*)&Bs[kB][nqB]     = *(const float4*)wp;
        *(float4*)&Bs[kB][nqB + 4] = *(const float4*)(wp + 4);
        __syncthreads();
        #pragma unroll
        for (int kk = 0; kk < 16; ++kk) {
            float4 a  = *(const float4*)&As[kk][tm];
            float4 b0 = *(const float4*)&Bs[kk][tn];
            float4 b1 = *(const float4*)&Bs[kk][tn + 64];
            float ar[4] = {a.x, a.y, a.z, a.w};
            float br[8] = {b0.x, b0.y, b0.z, b0.w, b1.x, b1.y, b1.z, b1.w};
            #pragma unroll
            for (int i2 = 0; i2 < 4; i2++)
                #pragma unroll
                for (int j = 0; j < 8; j++) acc[i2][j] += ar[i2] * br[j];
        }
        __syncthreads();
    }
    #pragma unroll
    for (int i2 = 0; i2 < 4; i2++) {
        int r = bm + tm + i2;
        if (r < Mc) {
            int row = ridx[tm + i2];
            float o[8];
            #pragma unroll
            for (int j = 0; j < 8; j++) {
                int cj = (j < 4) ? (tn + j) : (64 + tn + j - 4);
                float x = acc[i2][j] + bias[bn + cj];
                if (RELU) x = fmaxf(x, 0.f);
                o[j] = x;
            }
            float* cp = C + (size_t)row * Nn + bn;
            *(float4*)(cp + tn)      = make_float4(o[0], o[1], o[2], o[3]);
            *(float4*)(cp + 64 + tn) = make_float4(o[4], o[5], o[6], o[7]);
        }
    }
}

// ---------------- pooling score ----------------
__global__ void score_kernel(const float* __restrict__ H, const float* __restrict__ Wp,
                             const float* __restrict__ bp, const float* __restrict__ mask,
                             float* __restrict__ scores, float* __restrict__ keys, int n) {
    int lane = threadIdx.x & 63;
    int node = blockIdx.x * 4 + (threadIdx.x >> 6);
    if (node >= n) return;
    float4 hv = ((const float4*)(H + (size_t)node * 256))[lane];
    float4 wq = ((const float4*)Wp)[lane];
    float d = hv.x * wq.x + hv.y * wq.y + hv.z * wq.z + hv.w * wq.w;
    #pragma unroll
    for (int off = 32; off > 0; off >>= 1) d += __shfl_down(d, off);
    if (lane == 0) {
        float sc = 1.f / (1.f + expf(-(d + bp[0])));
        scores[node] = sc;
        keys[node] = (mask && mask[node] == 0.f) ? -1e9f : sc;
    }
}

// ---------------- top-K selection ----------------
__device__ __forceinline__ unsigned key_u(float f) {
    unsigned u = __float_as_uint(f);
    return (u & 0x80000000u) ? ~u : (u | 0x80000000u);
}

__device__ __forceinline__ void wave_hist_add(int* __restrict__ hist, unsigned bin, bool valid) {
    int lane = threadIdx.x & 63;
    while (true) {
        unsigned long long vmask = __ballot(valid);
        if (vmask == 0ull) break;
        int leader = __ffsll((long long)vmask) - 1;
        unsigned lbin = (unsigned)__shfl((int)bin, leader);
        bool match = valid && (bin == lbin);
        unsigned long long mmask = __ballot(match);
        if (lane == leader) atomicAdd(&hist[lbin], __popcll(mmask));
        if (match) valid = false;
    }
}

// Wave-aggregated list append (one atomic per wave)
__device__ __forceinline__ void wave_append(int* __restrict__ cnt, int* __restrict__ list,
                                            bool pred, int val) {
    int lane = threadIdx.x & 63;
    unsigned long long m = __ballot(pred);
    if (m == 0ull) return;
    int leader = __ffsll((long long)m) - 1;
    int base = 0;
    if (lane == leader) base = atomicAdd(cnt, __popcll(m));
    base = __shfl(base, leader);
    if (pred) list[base + __popcll(m & ((1ull << lane) - 1ull))] = val;
}

// -------- fallback: single block radix select --------
__global__ void topk_kernel(const float* __restrict__ keys, const float* __restrict__ scores,
                            float* __restrict__ nm, float* __restrict__ gate, int n, int K) {
    __shared__ int hist[256];
    __shared__ unsigned sh_prefix;
    __shared__ int sh_krem;
    __shared__ int sh_running;
    __shared__ int wsum[16];
    int tid = threadIdx.x, lane = tid & 63, wid = tid >> 6;
    if (tid == 0) { sh_prefix = 0u; sh_krem = K; sh_running = 0; }
    __syncthreads();
    for (int pass = 0; pass < 4; ++pass) {
        int shift = 24 - pass * 8;
        if (tid < 256) hist[tid] = 0;
        __syncthreads();
        unsigned pmask = (pass == 0) ? 0u : (0xFFFFFFFFu << (shift + 8));
        unsigned prefix = sh_prefix;
        for (int i = tid; i < n; i += 1024) {
            unsigned u = key_u(keys[i]);
            if ((u & pmask) == prefix) atomicAdd(&hist[(u >> shift) & 0xFF], 1);
        }
        __syncthreads();
        if (tid == 0) {
            int krem = sh_krem;
            int b;
            for (b = 255; b > 0; --b) {
                int c = hist[b];
                if (c >= krem) break;
                krem -= c;
            }
            sh_prefix = prefix | ((unsigned)b << shift);
            sh_krem = krem;
        }
        __syncthreads();
    }
    unsigned Tkey = sh_prefix;
    int need_eq = sh_krem;
    for (int base = 0; base < n; base += 1024) {
        int i = base + tid;
        unsigned u = 0; int flagv = 0;
        if (i < n) { u = key_u(keys[i]); flagv = (u == Tkey) ? 1 : 0; }
        unsigned long long bal = __ballot(flagv);
        int rank_w = __popcll(bal & ((1ull << lane) - 1ull));
        if (lane == 63) wsum[wid] = __popcll(bal);
        __syncthreads();
        int woff = 0;
        for (int w = 0; w < wid; ++w) woff += wsum[w];
        int grank = sh_running + woff + rank_w;
        if (i < n) {
            float v = (u > Tkey) ? 1.f : ((flagv && grank < need_eq) ? 1.f : 0.f);
            nm[i] = v;
            gate[i] = v * scores[i];
        }
        __syncthreads();
        if (tid == 0) {
            int tot = 0;
            for (int w = 0; w < 16; ++w) tot += wsum[w];
            sh_running += tot;
        }
        __syncthreads();
    }
}

// -------- fast path: grid-wide radix select, 2 passes of 16 bits --------
__global__ void topk_hist1(const float* __restrict__ keys, int n, int* __restrict__ hist) {
    int i = blockIdx.x * blockDim.x + threadIdx.x;
    unsigned bin = 0; bool valid = (i < n);
    if (valid) bin = key_u(keys[i]) >> 16;
    wave_hist_add(hist, bin, valid);
}

// scan1: finds threshold bucket; zeroes its own bins afterward.
__global__ void topk_scan1(int* __restrict__ hist, int K, int* __restrict__ sel) {
    __shared__ int arr[1024];
    int tid = threadIdx.x;
    int base = tid * 64;
    int local = 0;
    #pragma unroll 8
    for (int b = 0; b < 64; ++b) local += hist[base + b];
    arr[tid] = local;
    __syncthreads();
    for (int off = 1; off < 1024; off <<= 1) {
        int v = (tid + off < 1024) ? arr[tid + off] : 0;
        __syncthreads();
        arr[tid] += v;
        __syncthreads();
    }
    int above = arr[tid] - local;
    if (above < K && arr[tid] >= K) {
        int run = above;
        for (int b = base + 63; b >= base; --b) {
            int c = hist[b];
            if (run + c >= K) { sel[0] = b; sel[1] = K - run; break; }
            run += c;
        }
    }
    #pragma unroll 8
    for (int b = 0; b < 64; ++b) hist[base + b] = 0;
}

__global__ void topk_hist2(const float* __restrict__ keys, int n, const int* __restrict__ sel,
                           int* __restrict__ hist) {
    int i = blockIdx.x * blockDim.x + threadIdx.x;
    unsigned bin = 0; bool valid = false;
    if (i < n) {
        unsigned u = key_u(keys[i]);
        if ((int)(u >> 16) == sel[0]) { bin = u & 0xFFFF; valid = true; }
    }
    wave_hist_add(hist, bin, valid);
}

// scan2: finds Tkey/need_eq, zeroes bins, resets tie + compaction counters.
__global__ void topk_scan2(int* __restrict__ hist, int* __restrict__ sel,
                           int* __restrict__ tie_cnt, int* __restrict__ ccnt) {
    __shared__ int arr[1024];
    int tid = threadIdx.x;
    if (tid == 0) { *tie_cnt = 0; *ccnt = 0; }
    int K = sel[1];
    int base = tid * 64;
    int local = 0;
    #pragma unroll 8
    for (int b = 0; b < 64; ++b) local += hist[base + b];
    arr[tid] = local;
    __syncthreads();
    for (int off = 1; off < 1024; off <<= 1) {
        int v = (tid + off < 1024) ? arr[tid + off] : 0;
        __syncthreads();
        arr[tid] += v;
        __syncthreads();
    }
    int above = arr[tid] - local;
    if (above < K && arr[tid] >= K) {
        int run = above;
        for (int b = base + 63; b >= base; --b) {
            int c = hist[b];
            if (run + c >= K) {
                sel[2] = (int)((((unsigned)sel[0]) << 16) | (unsigned)b);
                sel[3] = K - run;
                break;
            }
            run += c;
        }
    }
    #pragma unroll 8
    for (int b = 0; b < 64; ++b) hist[base + b] = 0;
}

// mark: writes nm/gate; wave-aggregated appends to selected + tie lists.
__global__ void topk_mark(const float* __restrict__ keys, const float* __restrict__ scores,
                          const int* __restrict__ sel, float* __restrict__ nm,
                          float* __restrict__ gate, int* __restrict__ tie_list,
                          int* __restrict__ tie_cnt, int* __restrict__ sidx,
                          int* __restrict__ ccnt, int n) {
    int i = blockIdx.x * blockDim.x + threadIdx.x;
    unsigned Tkey = (unsigned)sel[2];
    bool in = (i < n);
    bool selp = false, tiep = false;
    if (in) {
        unsigned u = key_u(keys[i]);
        selp = (u > Tkey);
        tiep = (u == Tkey);
        float v = selp ? 1.f : 0.f;
        nm[i] = v;
        gate[i] = v * scores[i];
    }
    wave_append(ccnt, sidx, selp, i);
    wave_append(tie_cnt, tie_list, tiep, i);
}

__global__ void topk_ties(const float* __restrict__ scores, const int* __restrict__ sel,
                          const int* __restrict__ tie_list, const int* __restrict__ tie_cnt,
                          float* __restrict__ nm, float* __restrict__ gate,
                          int* __restrict__ sidx, int* __restrict__ ccnt) {
    int cnt = *tie_cnt;
    int need = sel[3];
    for (int j = threadIdx.x; j < cnt; j += blockDim.x) {
        int idx = tie_list[j];
        int rank = 0;
        for (int k2 = 0; k2 < cnt; ++k2) rank += (tie_list[k2] < idx) ? 1 : 0;
        if (rank < need) {
            nm[idx] = 1.f; gate[idx] = scores[idx];
            int p = atomicAdd(ccnt, 1); sidx[p] = idx;   // tie count tiny
        }
    }
}

// ---------------- adds ----------------
__global__ void add_mask_kernel(float* __restrict__ A, const float* __restrict__ B,
                                const float* __restrict__ mask, int n4) {
    int i = blockIdx.x * blockDim.x + threadIdx.x;
    if (i < n4) {
        float4 a = ((float4*)A)[i];
        float4 b = ((const float4*)B)[i];
        if (mask && mask[i >> 6] == 0.f) { a.x = 0.f; a.y = 0.f; a.z = 0.f; a.w = 0.f; }
        a.x += b.x; a.y += b.y; a.z += b.z; a.w += b.w;
        ((float4*)A)[i] = a;
    }
}

extern "C" void kernel_launch(void* const* d_in, const int* in_sizes, int n_in,
                              void* d_out, int out_size, void* d_ws, size_t ws_size,
                              hipStream_t stream) {
    const int n = in_sizes[0] / 128;   // 50000
    const int E = in_sizes[1];         // 800000
    const int NPAD = ((n + 63) / 64) * 64;
    const int K1 = 25000, K2 = 12500;

    const float* features = (const float*)d_in[0];
    const int* src = (const int*)d_in[1];
    const int* dst = (const int*)d_in[2];
    const float* W_embed = (const float*)d_in[3];
    const float* b_embed = (const float*)d_in[4];
    const float* W_enc0  = (const float*)d_in[5];
    const float* b_enc0  = (const float*)d_in[6];
    const float* W_enc1  = (const float*)d_in[7];
    const float* b_enc1  = (const float*)d_in[8];
    const float* W_p0    = (const float*)d_in[9];
    const float* b_p0    = (const float*)d_in[10];
    const float* W_p1    = (const float*)d_in[11];
    const float* b_p1    = (const float*)d_in[12];
    const float* W_bot   = (const float*)d_in[13];
    const float* b_bot   = (const float*)d_in[14];
    const float* W_dec0  = (const float*)d_in[15];
    const float* b_dec0  = (const float*)d_in[16];
    const float* W_dec1  = (const float*)d_in[17];
    const float* b_dec1  = (const float*)d_in[18];
    float* out_f = (float*)d_out;

    char* ws = (char*)d_ws;
    size_t off = 0;
    auto alloc = [&](size_t bytes) -> void* {
        void* p = ws + off;
        off += (bytes + 255) & ~(size_t)255;
        return p;
    };
    (void)alloc(256);  // pad
    int* row_ptr  = (int*)alloc((size_t)(n + 1) * 4);
    int* cursor   = (int*)alloc((size_t)n * 4);
    int* col      = (int*)alloc((size_t)E * 4);
    int* deg_out_i= (int*)alloc((size_t)n * 4);
    int* deg_in_i = (int*)alloc((size_t)n * 4);
    float* so_m1  = (float*)alloc((size_t)n * 4);
    float* si_m1  = (float*)alloc((size_t)n * 4);
    float* so_m2  = (float*)alloc((size_t)n * 4);
    float* si_m2  = (float*)alloc((size_t)n * 4);
    float* sarr   = (float*)alloc((size_t)n * 4);
    float* tarr   = (float*)alloc((size_t)n * 4);
    float* scores1= (float*)alloc((size_t)n * 4);
    float* keys1  = (float*)alloc((size_t)n * 4);
    float* scores2= (float*)alloc((size_t)n * 4);
    float* keys2  = (float*)alloc((size_t)n * 4);
    float* nm1    = (float*)alloc((size_t)n * 4);
    float* gate1  = (float*)alloc((size_t)n * 4);
    float* nm2    = (float*)alloc((size_t)n * 4);
    float* gate2  = (float*)alloc((size_t)n * 4);
    size_t big = (size_t)NPAD * 256 * 4;
    float* A = (float*)alloc(big);
    float* B = (float*)alloc(big);
    float* C = (float*)alloc(big);
    float* D = (float*)alloc(big);
    // ---- tail ----
    int* rhist    = (int*)alloc(65536 * 4);
    int* sel      = (int*)alloc(256);
    int* tie_cnt  = (int*)alloc(256);
    int* tie_list = (int*)alloc((size_t)n * 4);
    float* s0     = (float*)alloc((size_t)n * 4);
    float* t0     = (float*)alloc((size_t)n * 4);
    int* idx1     = (int*)alloc((size_t)n * 4);
    int* idx2     = (int*)alloc((size_t)n * 4);
    int* ccnt     = (int*)alloc(256);
    bool fast = (off <= ws_size);

    dim3 blk(256);
    int gE = (E + 255) / 256;
    int gN = (n + 255) / 256;
    int gAgg256 = (n + 3) / 4;
    int gAgg128 = (n + 7) / 8;
    int gAggK1 = (K1 + 3) / 4;
    int gAggK2 = (K2 + 3) / 4;
    int gScore = (n + 3) / 4;
    dim3 gemm_g(NPAD / 64, 2);
    dim3 gemm_g128(NPAD / 64, 1);
    dim3 gemm_gK1((K1 + 63) / 64, 2);
    dim3 gemm_gK2((K2 + 63) / 64, 2);
    int gAdd = (n * 64 + 255) / 256;

    auto run_topk = [&](const float* keys, const float* scores, float* nm, float* gate,
                        int K, int* sidx, int* cc) {
        if (fast) {
            topk_hist1<<<gN, blk, 0, stream>>>(keys, n, rhist);
            topk_scan1<<<1, 1024, 0, stream>>>(rhist, K, sel);
            topk_hist2<<<gN, blk, 0, stream>>>(keys, n, sel, rhist);
            topk_scan2<<<1, 1024, 0, stream>>>(rhist, sel, tie_cnt, cc);
            topk_mark<<<gN, blk, 0, stream>>>(keys, scores, sel, nm, gate, tie_list, tie_cnt,
                                              sidx, cc, n);
            topk_ties<<<1, 256, 0, stream>>>(scores, sel, tie_list, tie_cnt, nm, gate, sidx, cc);
        } else {
            topk_kernel<<<1, 1024, 0, stream>>>(keys, scores, nm, gate, n, K);
        }
    };
    float* sF = fast ? s0 : sarr;
    float* tF = fast ? t0 : tarr;

    // ---- CSR build (dst-CSR only; R16 reverts the src-CSR/deg_scale regression) ----
    hipMemsetAsync(deg_out_i, 0, (size_t)n * 4, stream);
    hipMemsetAsync(deg_in_i, 0, (size_t)n * 4, stream);
    if (fast) hipMemsetAsync(rhist, 0, 65536 * 4, stream);   // scans re-zero afterward
    hist_kernel<<<gE, blk, 0, stream>>>(src, dst, deg_out_i, deg_in_i, E);
    scan_kernel<<<1, 1024, 0, stream>>>(deg_in_i, row_ptr, cursor, n);
    fill_kernel<<<gE, blk, 0, stream>>>(src, dst, cursor, col, E);
    sort_rows_kernel<<<gN, blk, 0, stream>>>(row_ptr, col, n);

    // ---- full-graph degree scales ----
    scale_full_kernel<<<gN, blk, 0, stream>>>(deg_out_i, deg_in_i, sF, tF, n);

    // ---- embed GCN (full graph) -> A ----
    agg_feat_128_kernel<<<gAgg128, blk, 0, stream>>>(row_ptr, col, features, sF, tF, D, n);
    gemm_kernel<true><<<gemm_g, blk, 0, stream>>>(D, W_embed, b_embed, nullptr, nullptr, A, n, 128, 256);

    // ---- enc0 (full graph); hidden0 = B ----
    agg_f32_256_kernel<false><<<gAgg256, blk, 0, stream>>>(row_ptr, col, A, sF, tF, D, n);
    gemm_kernel<true><<<gemm_g, blk, 0, stream>>>(D, W_enc0, b_enc0, nullptr, nullptr, B, n, 256, 256);

    // ---- pool0 ----
    score_kernel<<<gScore, blk, 0, stream>>>(B, W_p0, b_p0, nullptr, scores1, keys1, n);
    run_topk(keys1, scores1, nm1, gate1, K1, idx1, ccnt);

    // ---- enc1 (mask m1, gated input); hidden1 = C ----
    hipMemsetAsync(so_m1, 0, (size_t)n * 4, stream);
    out_deg_mask_kernel<<<gE, blk, 0, stream>>>(src, dst, nm1, so_m1, E);
    in_deg_mask_kernel<<<gN, blk, 0, stream>>>(row_ptr, col, nm1, si_m1, n);
    scale_mask_kernel<<<gN, blk, 0, stream>>>(gate1, nm1, so_m1, si_m1, sarr, tarr, n);
    if (fast) {
        agg_rows_256_kernel<<<gAggK1, blk, 0, stream>>>(row_ptr, col, B, sarr, tarr, idx1, K1, D);
        gemm_rows_kernel<true><<<gemm_gK1, blk, 0, stream>>>(D, W_enc1, b_enc1, idx1, K1, C, 256, 256);
    } else {
        agg_f32_256_kernel<true><<<gAgg256, blk, 0, stream>>>(row_ptr, col, B, sarr, tarr, D, n);
        gemm_kernel<true><<<gemm_g, blk, 0, stream>>>(D, W_enc1, b_enc1, nm1, nullptr, C, n, 256, 256);
    }

    // ---- pool1 ----
    score_kernel<<<gScore, blk, 0, stream>>>(C, W_p1, b_p1, nm1, scores2, keys2, n);
    run_topk(keys2, scores2, nm2, gate2, K2, idx2, ccnt + 1);

    // ---- bottleneck (mask m2, gated input) -> A ----
    hipMemsetAsync(so_m2, 0, (size_t)n * 4, stream);
    out_deg_mask_kernel<<<gE, blk, 0, stream>>>(src, dst, nm2, so_m2, E);
    in_deg_mask_kernel<<<gN, blk, 0, stream>>>(row_ptr, col, nm2, si_m2, n);
    scale_mask_kernel<<<gN, blk, 0, stream>>>(gate2, nm2, so_m2, si_m2, sarr, tarr, n);
    if (fast) {
        agg_rows_256_kernel<<<gAggK2, blk, 0, stream>>>(row_ptr, col, C, sarr, tarr, idx2, K2, D);
        gemm_rows_kernel<true><<<gemm_gK2, blk, 0, stream>>>(D, W_bot, b_bot, idx2, K2, A, 256, 256);
    } else {
        agg_f32_256_kernel<true><<<gAgg256, blk, 0, stream>>>(row_ptr, col, C, sarr, tarr, D, n);
        gemm_kernel<true><<<gemm_g, blk, 0, stream>>>(D, W_bot, b_bot, nm2, nullptr, A, n, 256, 256);
    }

    // ---- dec0: h = (m2? bot : 0) + hidden1, GCN mask m1 -> A ----
    add_mask_kernel<<<gAdd, blk, 0, stream>>>(A, C, fast ? nm2 : nullptr, n * 64);
    scale_mask_kernel<<<gN, blk, 0, stream>>>(nm1, nm1, so_m1, si_m1, sarr, tarr, n);
    if (fast) {
        agg_rows_256_kernel<<<gAggK1, blk, 0, stream>>>(row_ptr, col, A, sarr, tarr, idx1, K1, D);
        gemm_rows_kernel<true><<<gemm_gK1, blk, 0, stream>>>(D, W_dec0, b_dec0, idx1, K1, A, 256, 256);
    } else {
        agg_f32_256_kernel<true><<<gAgg256, blk, 0, stream>>>(row_ptr, col, A, sarr, tarr, D, n);
        gemm_kernel<true><<<gemm_g, blk, 0, stream>>>(D, W_dec0, b_dec0, nm1, nullptr, A, n, 256, 256);
    }

    // ---- dec1 (reordered, final layer) ----
    add_mask_kernel<<<gAdd, blk, 0, stream>>>(A, B, fast ? nm1 : nullptr, n * 64);
    if (!fast)
        scale_full_kernel<<<gN, blk, 0, stream>>>(deg_out_i, deg_in_i, sarr, tarr, n);
    gemm_kernel<false><<<gemm_g128, blk, 0, stream>>>(A, W_dec1, nullptr, nullptr, sF, C, n, 256, 128);
    agg_bias_128_kernel<<<gAgg128, blk, 0, stream>>>(row_ptr, col, C, tF, b_dec1, out_f, n);

    (void)n_in; (void)out_size;
}